// Round 12
// baseline (3134.587 us; speedup 1.0000x reference)
//
#include <hip/hip_runtime.h>
#include <hip/hip_bf16.h>

// ---------------------------------------------------------------------------
// FaceXHuBERT decoder: 2-layer GRU (H=256) over T=512 + fc to V=70110 with
// teacher-forcing feedback through red_w [A=768, V].
//
// Pipeline:
//   tobf16 x3:   redw/vert -> padded bf16 (stride 70144, zeroed pad), fcw -> bf16
//   bigk_bf16:   OUT_G = red_w@vert^T, OUT_M = red_w@fc_w via global_load_lds
//                staging (no VALU convert) — m97-style. Fallback f32 path if
//                ws_size too small.
//   gemv3 / transpose_merged / gemm128x3 (round 10)
//   k3_fused:    32 producer WGs (round-10 schedule — measured best) + 224
//                consumer WGs (fc GEMM + MSE, bf16 fcw staging)
//   loss_finalize
// ---------------------------------------------------------------------------

#define TT 512
#define VD 70110
#define VDP 70144   // padded bf16 row stride (mult of 32 elems, 16B aligned)
#define NR 1024

using bf16x8 = __attribute__((ext_vector_type(8))) short;
using f32x4  = __attribute__((ext_vector_type(4))) float;

static __device__ __forceinline__ unsigned short f2bf(float f) {
  unsigned u = __float_as_uint(f);
  u += 0x7FFFu + ((u >> 16) & 1u);   // RNE
  return (unsigned short)(u >> 16);
}

// ---------------- f32 -> bf16 conversion with optional padded/zeroed tail ---
__global__ __launch_bounds__(256)
void tobf16(const float* __restrict__ src, unsigned short* __restrict__ dst,
            long srcStride, long dstStride, int colsSrc, int colsDst)
{
  const long row = blockIdx.y;
  const int c0 = (blockIdx.x * 256 + threadIdx.x) * 8;
  if (c0 >= colsDst) return;
  const float* s = src + row * srcStride;
  unsigned short* d = dst + row * dstStride;
  if (c0 + 8 <= colsSrc) {
    const float2* s2 = (const float2*)(s + c0);
    unsigned short t[8] __attribute__((aligned(16)));
#pragma unroll
    for (int i = 0; i < 4; ++i) { float2 v = s2[i]; t[2*i] = f2bf(v.x); t[2*i+1] = f2bf(v.y); }
    *(int4*)(d + c0) = *(int4*)t;
  } else {
#pragma unroll
    for (int i = 0; i < 8; ++i) {
      int c = c0 + i;
      if (c < colsDst) d[c] = (c < colsSrc) ? f2bf(s[c]) : (unsigned short)0;
    }
  }
}

// ---------------- bigk via bf16 + global_load_lds staging -------------------
// blockIdx.x<4: OUTG (B = VB rows, N=1024); ==4: OUTM (B = FB k-major, N=256)
__global__ __launch_bounds__(512, 1)
void bigk_bf16(const unsigned short* __restrict__ RB,
               const unsigned short* __restrict__ VB,
               const unsigned short* __restrict__ FB,
               float* __restrict__ OUTG, float* __restrict__ OUTM, int CHK)
{
  __shared__ unsigned short Al[256][32];
  __shared__ unsigned short Bl[256][32];
  const int tid = threadIdx.x;
  const bool bform = (blockIdx.x == 4);
  float* C      = bform ? OUTM : OUTG;
  const int ldc = bform ? 256 : 1024;
  const int n0  = bform ? 0 : blockIdx.x * 256;
  const int m0  = blockIdx.y * 256;
  const int kc0 = blockIdx.z * CHK;
  const int kc1 = min(VDP, kc0 + CHK);     // mult of 32 by construction
  const int wave = tid >> 6, lane = tid & 63;
  const int wm = wave >> 1, wn = wave & 1;
  const int kq = lane >> 4, ln = lane & 15;
  const int rowL = tid >> 2, segL = tid & 3;   // lane's staging row/segment
  f32x4 acc[4][8] = {};
  for (int kc = kc0; kc < kc1; kc += 32) {
    __syncthreads();
    // stage A: 256 rows x 32 bf16 via global_load_lds (2 issues x 8KB)
    {
      void* ldsA = (void*)((char*)&Al[0][0] + (tid >> 6) * 1024);
#pragma unroll
      for (int iss = 0; iss < 2; ++iss) {
        const int gL = iss * 512 + tid;
        const int row = gL >> 2, seg = gL & 3;
        const unsigned short* src = RB + (long)(m0 + row) * VDP + kc + seg * 8;
        __builtin_amdgcn_global_load_lds((const void*)src,
                                         (void*)((char*)ldsA + iss * 8192), 16, 0, 0);
      }
      (void)rowL; (void)segL;
    }
    if (!bform) { // stage B: vert-bf16 rows, same pattern
      void* ldsB = (void*)((char*)&Bl[0][0] + (tid >> 6) * 1024);
#pragma unroll
      for (int iss = 0; iss < 2; ++iss) {
        const int gL = iss * 512 + tid;
        const int row = gL >> 2, seg = gL & 3;
        const unsigned short* src = VB + (long)(n0 + row) * VDP + kc + seg * 8;
        __builtin_amdgcn_global_load_lds((const void*)src,
                                         (void*)((char*)ldsB + iss * 8192), 16, 0, 0);
      }
    } else {      // stage B from k-major FB (transpose into LDS), guarded
      const int n = tid & 255, kh = (tid >> 8) << 4;
#pragma unroll
      for (int i = 0; i < 16; ++i) {
        const int kk = kc + kh + i;
        Bl[n][kh + i] = (kk < VD) ? FB[(long)kk * 256 + n] : (unsigned short)0;
      }
    }
    __syncthreads();
    bf16x8 af[4], bfv[8];
#pragma unroll
    for (int i = 0; i < 4; ++i) af[i] = *(const bf16x8*)&Al[wm*64 + i*16 + ln][kq*8];
#pragma unroll
    for (int j = 0; j < 8; ++j) bfv[j] = *(const bf16x8*)&Bl[wn*128 + j*16 + ln][kq*8];
#pragma unroll
    for (int i = 0; i < 4; ++i)
#pragma unroll
      for (int j = 0; j < 8; ++j)
        acc[i][j] = __builtin_amdgcn_mfma_f32_16x16x32_bf16(af[i], bfv[j], acc[i][j], 0, 0, 0);
  }
#pragma unroll
  for (int i = 0; i < 4; ++i)
#pragma unroll
    for (int j = 0; j < 8; ++j)
#pragma unroll
      for (int r = 0; r < 4; ++r) {
        const int gm = m0 + wm*64 + i*16 + kq*4 + r;
        const int gn = n0 + wn*128 + j*16 + ln;
        unsafeAtomicAdd(&C[(long)gm * ldc + gn], acc[i][j][r]);
      }
}

// ---------------- fallback: merged big split-K GEMM (f32 inputs) ------------
__global__ __launch_bounds__(512, 1)
void bigk_merged(const float* __restrict__ A, const float* __restrict__ vert,
                 const float* __restrict__ fcw,
                 float* __restrict__ OUTG, float* __restrict__ OUTM, int CHK)
{
  __shared__ unsigned short Al[256][40];
  __shared__ unsigned short Bl[256][40];
  const int tid = threadIdx.x;
  const bool bform = (blockIdx.x == 4);
  float* C      = bform ? OUTM : OUTG;
  const int ldc = bform ? 256 : 1024;
  const int N   = bform ? 256 : 1024;
  const int n0  = bform ? 0 : blockIdx.x * 256;
  const int m0  = blockIdx.y * 256;
  const int kc0 = blockIdx.z * CHK;
  const int kc1 = min(VD, kc0 + CHK);
  const int wave = tid >> 6, lane = tid & 63;
  const int wm = wave >> 1, wn = wave & 1;
  const int kq = lane >> 4, ln = lane & 15;
  f32x4 acc[4][8] = {};
  for (int kc = kc0; kc < kc1; kc += 32) {
    __syncthreads();
    {
      const int m = tid >> 1, kh = (tid & 1) << 4;
      const float* arow = A + (long)(m0 + m) * (long)VD;
      unsigned short tmp[16] __attribute__((aligned(16)));
      if (kc + 32 <= kc1) {
        const float2* ap2 = (const float2*)(arow + kc + kh);
#pragma unroll
        for (int i = 0; i < 8; ++i) { float2 v = ap2[i]; tmp[2*i] = f2bf(v.x); tmp[2*i+1] = f2bf(v.y); }
      } else {
#pragma unroll
        for (int i = 0; i < 16; ++i) {
          int kk = kc + kh + i;
          tmp[i] = f2bf((kk < kc1) ? arow[kk] : 0.f);
        }
      }
      ((int4*)&Al[m][kh])[0] = *(int4*)&tmp[0];
      ((int4*)&Al[m][kh])[1] = *(int4*)&tmp[8];
    }
    if (!bform) {
      const int n = tid >> 1, kh = (tid & 1) << 4;
      const float* bp = vert + (long)(n0 + n) * (long)VD;
      unsigned short tmp[16] __attribute__((aligned(16)));
      if (kc + 32 <= kc1) {
        const float2* bp2 = (const float2*)(bp + kc + kh);
#pragma unroll
        for (int i = 0; i < 8; ++i) { float2 v = bp2[i]; tmp[2*i] = f2bf(v.x); tmp[2*i+1] = f2bf(v.y); }
      } else {
#pragma unroll
        for (int i = 0; i < 16; ++i) {
          int kk = kc + kh + i;
          tmp[i] = f2bf((kk < kc1) ? bp[kk] : 0.f);
        }
      }
      ((int4*)&Bl[n][kh])[0] = *(int4*)&tmp[0];
      ((int4*)&Bl[n][kh])[1] = *(int4*)&tmp[8];
    } else {
      const int n = tid & 255, kh = (tid >> 8) << 4;
      unsigned short tmp[16] __attribute__((aligned(16)));
#pragma unroll
      for (int i = 0; i < 16; ++i) {
        int kk = kc + kh + i;
        float v = 0.f;
        if (kk < kc1 && n < 256) v = fcw[(long)kk * 256 + n];
        tmp[i] = f2bf(v);
      }
      ((int4*)&Bl[n][kh])[0] = *(int4*)&tmp[0];
      ((int4*)&Bl[n][kh])[1] = *(int4*)&tmp[8];
    }
    __syncthreads();
    bf16x8 af[4], bfv[8];
#pragma unroll
    for (int i = 0; i < 4; ++i) af[i] = *(const bf16x8*)&Al[wm*64 + i*16 + ln][kq*8];
#pragma unroll
    for (int j = 0; j < 8; ++j) bfv[j] = *(const bf16x8*)&Bl[wn*128 + j*16 + ln][kq*8];
#pragma unroll
    for (int i = 0; i < 4; ++i)
#pragma unroll
      for (int j = 0; j < 8; ++j)
        acc[i][j] = __builtin_amdgcn_mfma_f32_16x16x32_bf16(af[i], bfv[j], acc[i][j], 0, 0, 0);
  }
#pragma unroll
  for (int i = 0; i < 4; ++i)
#pragma unroll
    for (int j = 0; j < 8; ++j)
#pragma unroll
      for (int r = 0; r < 4; ++r) {
        int gm = m0 + wm*64 + i*16 + kq*4 + r;
        int gn = n0 + wn*128 + j*16 + ln;
        if (gn < N) unsafeAtomicAdd(&C[(long)gm * ldc + gn], acc[i][j][r]);
      }
}

// ---------------- gemv3: EXTRA[v][a] = sum_k {tmpl0,tmpl1,fcb}[k]*redw[a][k]
__global__ __launch_bounds__(256)
void gemv3(const float* __restrict__ redw, const float* __restrict__ tmpl,
           const float* __restrict__ fcb, float* __restrict__ extra)
{
  const int tid = threadIdx.x;
  const int a0 = blockIdx.x * 8;
  const long k0 = (long)blockIdx.y * 8764;
  const long k1 = (k0 + 8764 < (long)VD) ? (k0 + 8764) : (long)VD;
  float s[3][8] = {};
  for (long k = k0 + tid; k < k1; k += 256) {
    const float c0 = tmpl[k], c1 = tmpl[(long)VD + k], cb2 = fcb[k];
#pragma unroll
    for (int r = 0; r < 8; ++r) {
      const float w = redw[(long)(a0 + r) * VD + k];
      s[0][r] += c0 * w; s[1][r] += c1 * w; s[2][r] += cb2 * w;
    }
  }
#pragma unroll
  for (int v = 0; v < 3; ++v)
#pragma unroll
    for (int r = 0; r < 8; ++r) {
      float x = s[v][r];
#pragma unroll
      for (int o = 32; o > 0; o >>= 1) x += __shfl_down(x, o);
      if ((tid & 63) == 0) unsafeAtomicAdd(&extra[v * 768 + a0 + r], x);
    }
}

// ---------------- merged transposes (+red_b fold) + GF odd-row fixup --------
static __device__ __forceinline__ void transpose_body(
    const float* src, int lds, float* dst, int ldd,
    int rows, int cols, const float* bias, int bx, int by)
{
  __shared__ float tile[32][33];
  const int rb = bx * 32, cb = by * 32;
  const int tx = threadIdx.x & 31, ty = threadIdx.x >> 5;
  for (int yy = ty; yy < 32; yy += 8) {
    int c = cb + yy, r = rb + tx;
    tile[yy][tx] = (c < cols && r < rows) ? src[(long)c * lds + r] : 0.f;
  }
  __syncthreads();
  for (int yy = ty; yy < 32; yy += 8) {
    int r = rb + yy, c = cb + tx;
    if (r < rows && c < cols)
      dst[(long)r * ldd + c] = tile[tx][yy] + (bias ? bias[c] : 0.f);
  }
}

__global__ void transpose_merged(const float* __restrict__ OUTG,
                                 const float* __restrict__ OUTM,
                                 const float* __restrict__ extra,
                                 const float* __restrict__ redb,
                                 float* __restrict__ GF, float* __restrict__ MT)
{
  if (blockIdx.z == 0) {
    transpose_body(OUTG, 1024, GF, 768, 1024, 768, redb, blockIdx.x, blockIdx.y);
  } else {
    if (blockIdx.x < 8) {
      transpose_body(OUTM, 256, MT, 768, 256, 768, nullptr, blockIdx.x, blockIdx.y);
    } else if (blockIdx.x == 8 && blockIdx.y == 0) {
      for (int i = threadIdx.x; i < 3 * 768; i += 256) {
        const int b = i / 768, a = i - b * 768;
        GF[(long)(1024 + b) * 768 + a] = extra[i] + redb[a];
      }
    }
  }
}

// ---------------- merged small GEMMs (gihs / PM / M2) -----------------------
__global__ __launch_bounds__(256, 2)
void gemm128x3(const float* __restrict__ hs, const float* __restrict__ wih0,
               float* __restrict__ GIHS, const float* __restrict__ bih0,
               const float* __restrict__ GF, float* __restrict__ PM,
               const float* __restrict__ MT, float* __restrict__ M2)
{
  const float *A, *B, *bias = nullptr; float* C;
  int lda, ldb, M, N, K; long ldc;
  if (blockIdx.z == 0) {
    if (blockIdx.x >= 8) return;
    A = hs; lda = 768; B = wih0; ldb = 1536; C = GIHS; ldc = 768; bias = bih0;
    M = 1024; N = 768; K = 768;
  } else if (blockIdx.z == 1) {
    A = GF; lda = 768; B = wih0 + 768; ldb = 1536; C = PM; ldc = 768;
    M = 1027; N = 768; K = 768;
  } else {
    if (blockIdx.x >= 6 || blockIdx.y >= 2) return;
    A = wih0 + 768; lda = 1536; B = MT; ldb = 768; C = M2; ldc = 256;
    M = 768; N = 256; K = 768;
  }
  __shared__ unsigned short Al[128][40];
  __shared__ unsigned short Bl[128][40];
  const int tid = threadIdx.x;
  const int m0 = blockIdx.x * 128, n0 = blockIdx.y * 128;
  const int wave = tid >> 6, lane = tid & 63;
  const int wm = wave >> 1, wn = wave & 1;
  const int kq = lane >> 4, ln = lane & 15;
  f32x4 acc[4][4] = {};
  for (int kc = 0; kc < K; kc += 32) {
    __syncthreads();
    {
      const int m = tid >> 1, kh = (tid & 1) << 4;
      unsigned short tmp[16] __attribute__((aligned(16)));
      const bool mok = (m0 + m) < M;
      if (mok) {
        const float4* ap4 = (const float4*)(A + (long)(m0 + m) * lda + kc + kh);
#pragma unroll
        for (int i = 0; i < 4; ++i) {
          float4 v = ap4[i];
          tmp[4*i+0] = f2bf(v.x); tmp[4*i+1] = f2bf(v.y);
          tmp[4*i+2] = f2bf(v.z); tmp[4*i+3] = f2bf(v.w);
        }
      } else {
#pragma unroll
        for (int i = 0; i < 16; ++i) tmp[i] = 0;
      }
      ((int4*)&Al[m][kh])[0] = *(int4*)&tmp[0];
      ((int4*)&Al[m][kh])[1] = *(int4*)&tmp[8];
      const int n = m;
      unsigned short tmb[16] __attribute__((aligned(16)));
      const bool nok = (n0 + n) < N;
      if (nok) {
        const float4* bp4 = (const float4*)(B + (long)(n0 + n) * ldb + kc + kh);
#pragma unroll
        for (int i = 0; i < 4; ++i) {
          float4 v = bp4[i];
          tmb[4*i+0] = f2bf(v.x); tmb[4*i+1] = f2bf(v.y);
          tmb[4*i+2] = f2bf(v.z); tmb[4*i+3] = f2bf(v.w);
        }
      } else {
#pragma unroll
        for (int i = 0; i < 16; ++i) tmb[i] = 0;
      }
      ((int4*)&Bl[n][kh])[0] = *(int4*)&tmb[0];
      ((int4*)&Bl[n][kh])[1] = *(int4*)&tmb[8];
    }
    __syncthreads();
    bf16x8 af[4], bfv[4];
#pragma unroll
    for (int i = 0; i < 4; ++i) af[i]  = *(const bf16x8*)&Al[wm*64 + i*16 + ln][kq*8];
#pragma unroll
    for (int j = 0; j < 4; ++j) bfv[j] = *(const bf16x8*)&Bl[wn*64 + j*16 + ln][kq*8];
#pragma unroll
    for (int i = 0; i < 4; ++i)
#pragma unroll
      for (int j = 0; j < 4; ++j)
        acc[i][j] = __builtin_amdgcn_mfma_f32_16x16x32_bf16(af[i], bfv[j], acc[i][j], 0, 0, 0);
  }
#pragma unroll
  for (int i = 0; i < 4; ++i)
#pragma unroll
    for (int j = 0; j < 4; ++j)
#pragma unroll
      for (int r = 0; r < 4; ++r) {
        const int gm = m0 + wm*64 + i*16 + kq*4 + r;
        const int gn = n0 + wn*64 + j*16 + ln;
        if (gm < M && gn < N) {
          float v = acc[i][j][r];
          if (bias) v += bias[gn];
          C[(long)gm * ldc + gn] = v;
        }
      }
}

// ---------------- fused recurrence + fc GEMM --------------------------------
struct ProdLds {
  float wq[24][260], wh0s[24][260], wi1s[24][260], wh1s[24][260];
  float h0c[2][256], h1c[2][256];
  float dotsS[2][2][3][8];
  int tfl[TT];
};
struct ConsLds {
  unsigned short As[128][264];
  unsigned short Bl[128][40];
  float wred[8];
};

#define HALF_DOTS(W, H, MS)                                                   \
  {                                                                           \
    const int g8_ = tid >> 3, l8_ = tid & 7;                                  \
    if (g8_ < 48) {                                                           \
      const int row_ = g8_ >> 1, bb_ = g8_ & 1;                               \
      const float4* w4_ = (const float4*)&(W)[row_][0];                       \
      const float4* h4_ = (const float4*)&(H)[bb_][0];                        \
      float s_ = 0.f;                                                         \
      _Pragma("unroll")                                                       \
      for (int i = 0; i < 8; ++i) {                                           \
        const float4 a_ = w4_[i * 8 + l8_], h_ = h4_[i * 8 + l8_];            \
        s_ += a_.x * h_.x + a_.y * h_.y + a_.z * h_.z + a_.w * h_.w;          \
      }                                                                       \
      s_ += __shfl_xor(s_, 1); s_ += __shfl_xor(s_, 2); s_ += __shfl_xor(s_, 4); \
      if (l8_ == 0) dotsS[MS][bb_][row_ >> 3][row_ & 7] = s_;                 \
    }                                                                         \
  }

#define POLL_ISSUE(buf, var)                                                  \
  unsigned long long var = __hip_atomic_load(&(buf)[tid], __ATOMIC_RELAXED, __HIP_MEMORY_SCOPE_AGENT);
#define POLL_FINISH(buf, var, dstLds, want)                                   \
  {                                                                           \
    const unsigned w_ = (unsigned)(want); int sp_ = 0;                        \
    while ((unsigned)(var >> 32) < w_ && ++sp_ < (1 << 15)) {                 \
      __builtin_amdgcn_s_sleep(1);                                            \
      var = __hip_atomic_load(&(buf)[tid], __ATOMIC_RELAXED, __HIP_MEMORY_SCOPE_AGENT); \
    }                                                                         \
    ((float*)dstLds)[tid] = __uint_as_float((unsigned)var);                   \
  }
#define POLLP(buf, dstLds, want)                                              \
  { POLL_ISSUE(buf, pw_); POLL_FINISH(buf, pw_, dstLds, want); }

__global__ __launch_bounds__(512, 1)
void k3_fused(const float* __restrict__ gihs, const float* __restrict__ Pm,
              const float* __restrict__ M2m,
              const float* __restrict__ whh0, const float* __restrict__ bhh0,
              const float* __restrict__ wih1, const float* __restrict__ bih1,
              const float* __restrict__ whh1, const float* __restrict__ bhh1,
              const int* __restrict__ tfm,
              unsigned short* __restrict__ h1sb,
              unsigned long long* __restrict__ h0p, unsigned long long* __restrict__ h1p,
              unsigned* __restrict__ prog,
              const float* __restrict__ fcw, const unsigned short* __restrict__ FB,
              int useFB,
              const float* __restrict__ fcb, const float* __restrict__ vert,
              float* __restrict__ out, float* __restrict__ lossp)
{
  __shared__ union { ProdLds p; ConsLds c; } U;
  const int tid = threadIdx.x;

  if (blockIdx.x >= 32) {
    // ================= CONSUMER: fc GEMM tile sweep ========================
    auto& C = U.c;
    const int idx = blockIdx.x - 32;
    int tx, memb, cnt;
    if (idx < 24)      { tx = 0; memb = (idx)      >> 1; cnt = 12; }
    else if (idx < 48) { tx = 1; memb = (idx - 24) >> 1; cnt = 12; }
    else if (idx < 96) { tx = 2; memb = (idx - 48) >> 1; cnt = 24; }
    else               { tx = 3; memb = (idx - 96) >> 1; cnt = 64; }
    const int b = idx & 1;
    const int nt0 = memb * 548 / cnt, nt1 = (memb + 1) * 548 / cnt;
    if (nt0 >= nt1) return;
    const unsigned want = (unsigned)((tx + 1) * 128);
    if (tid < 32) {
      int sp = 0;
      while (__hip_atomic_load(&prog[tid * 16], __ATOMIC_RELAXED, __HIP_MEMORY_SCOPE_AGENT) < want) {
        if (++sp > (1 << 14)) break;
        for (int j = 0; j < 16; ++j) __builtin_amdgcn_s_sleep(15);
      }
    }
    __syncthreads();
    const long rbase = (long)b * 512 + (long)tx * 128;
    {
      const unsigned long long* src = (const unsigned long long*)(h1sb + rbase * 256);
#pragma unroll
      for (int i = 0; i < 16; ++i) {
        const int u = tid * 16 + i;
        unsigned long long v = __hip_atomic_load(&src[u], __ATOMIC_RELAXED, __HIP_MEMORY_SCOPE_AGENT);
        const int row = u >> 6, c4 = u & 63;
        *(unsigned long long*)&C.As[row][c4 * 4] = v;
      }
    }
    __syncthreads();
    const int wave = tid >> 6, lane = tid & 63;
    const int wm = wave >> 2, wn = wave & 3;
    const int kq = lane >> 4, ln = lane & 15;
    for (int nt = nt0; nt < nt1; ++nt) {
      const int n0 = nt * 128;
      f32x4 acc[4][2] = {};
#pragma unroll 1
      for (int ks = 0; ks < 8; ++ks) {
        __syncthreads();
        {
          const int rn = tid >> 2, kh = (tid & 3) * 8;
          const int gn = n0 + rn;
          if (useFB) {
            int4 v = {0, 0, 0, 0};
            if (gn < VD) v = *(const int4*)(FB + (long)gn * 256 + ks * 32 + kh);
            *(int4*)&C.Bl[rn][kh] = v;
          } else {
            unsigned short tmb[8] __attribute__((aligned(16)));
            if (gn < VD) {
              const float4* bp = (const float4*)&fcw[(long)gn * 256 + ks * 32 + kh];
              float4 v0 = bp[0], v1 = bp[1];
              tmb[0] = f2bf(v0.x); tmb[1] = f2bf(v0.y); tmb[2] = f2bf(v0.z); tmb[3] = f2bf(v0.w);
              tmb[4] = f2bf(v1.x); tmb[5] = f2bf(v1.y); tmb[6] = f2bf(v1.z); tmb[7] = f2bf(v1.w);
            } else {
#pragma unroll
              for (int i = 0; i < 8; ++i) tmb[i] = 0;
            }
            *(int4*)&C.Bl[rn][kh] = *(int4*)tmb;
          }
        }
        __syncthreads();
        bf16x8 af[4], bfv[2];
#pragma unroll
        for (int i = 0; i < 4; ++i)
          af[i] = *(const bf16x8*)&C.As[wm*64 + i*16 + ln][ks*32 + kq*8];
#pragma unroll
        for (int j = 0; j < 2; ++j)
          bfv[j] = *(const bf16x8*)&C.Bl[wn*32 + j*16 + ln][kq*8];
#pragma unroll
        for (int i = 0; i < 4; ++i)
#pragma unroll
          for (int j = 0; j < 2; ++j)
            acc[i][j] = __builtin_amdgcn_mfma_f32_16x16x32_bf16(af[i], bfv[j], acc[i][j], 0, 0, 0);
      }
      float ls = 0.f;
#pragma unroll
      for (int i = 0; i < 4; ++i)
#pragma unroll
        for (int j = 0; j < 2; ++j)
#pragma unroll
          for (int r = 0; r < 4; ++r) {
            const int gmL = wm*64 + i*16 + kq*4 + r;
            const int gn = n0 + wn*32 + j*16 + ln;
            if (gn < VD) {
              const float v = acc[i][j][r] + fcb[gn];
              const long grow = rbase + gmL;
              out[grow * VD + gn] = v;
              const float dd = v - vert[grow * VD + gn];
              ls += dd * dd;
            }
          }
#pragma unroll
      for (int o = 32; o > 0; o >>= 1) ls += __shfl_down(ls, o);
      if (lane == 0) C.wred[wave] = ls;
      __syncthreads();
      if (tid == 0) {
        float s = 0.f;
#pragma unroll
        for (int w = 0; w < 8; ++w) s += C.wred[w];
        lossp[(tx * 2 + b) * 548 + nt] = s;
      }
      __syncthreads();
    }
    return;
  }

  // ================= PRODUCER: round-10 schedule ===========================
  float (&wq)[24][260]   = U.p.wq;
  float (&wh0s)[24][260] = U.p.wh0s;
  float (&wi1s)[24][260] = U.p.wi1s;
  float (&wh1s)[24][260] = U.p.wh1s;
  float (&h0c)[2][256]   = U.p.h0c;
  float (&h1c)[2][256]   = U.p.h1c;
  float (&dotsS)[2][2][3][8] = U.p.dotsS;
  int   (&tfl)[TT]       = U.p.tfl;
  const int wg = blockIdx.x;
  const int j0 = wg * 8;

  {
    const int col = tid & 255, rh = tid >> 8;
    for (int row = rh; row < 24; row += 2) {
      const int g = row >> 3, jj = row & 7;
      const long gr = g * 256 + j0 + jj;
      wq[row][col]   = M2m[gr * 256 + col];
      wh0s[row][col] = whh0[gr * 256 + col];
      wi1s[row][col] = wih1[gr * 256 + col];
      wh1s[row][col] = whh1[gr * 256 + col];
    }
  }
  ((float*)h0c)[tid] = 0.f;
  ((float*)h1c)[tid] = 0.f;
  if (tid < TT) tfl[tid] = tfm[tid];

  const int cb = tid >> 3, cjj = tid & 7, cj = j0 + cjj;
  float bh0v[3], bi1v[3], bh1v[3], d2v[3];
  if (tid < 16) {
#pragma unroll
    for (int g = 0; g < 3; ++g) {
      bh0v[g] = bhh0[g*256 + cj];
      bi1v[g] = bih1[g*256 + cj];
      bh1v[g] = bhh1[g*256 + cj];
      d2v[g]  = Pm[(long)1026 * 768 + g*256 + cj];
    }
  }
  __syncthreads();

  const int wave = tid >> 6;
  float gihsv[3], piv[3];
  if (tid < 16) {
#pragma unroll
    for (int g = 0; g < 3; ++g) {
      gihsv[g] = gihs[((long)cb * TT) * 768 + g*256 + cj];
      piv[g]   = Pm[(long)(1024 + cb) * 768 + g*256 + cj];
    }
  }
  for (int t = 0; t < TT; ++t) {
    const int tfprev = (t == 0) ? 1 : tfl[t - 1];
    // ---- phase A
    if (!tfprev) {
      POLL_ISSUE(h1p + (t & 1) * 512, pb);
      HALF_DOTS(wh0s, h0c, 1);
      POLL_FINISH(h1p + (t & 1) * 512, pb, h1c, t);
      __syncthreads();
      HALF_DOTS(wq, h1c, 0);
    } else {
      HALF_DOTS(wh0s, h0c, 1);
    }
    __syncthreads();
    if (tid < 16) {
      float gi[3], gh[3];
#pragma unroll
      for (int g = 0; g < 3; ++g) {
        const float q = tfprev ? 0.f : (dotsS[0][cb][g][cjj] + d2v[g]);
        gi[g] = gihsv[g] + (tfprev ? piv[g] : q);
        gh[g] = dotsS[1][cb][g][cjj] + bh0v[g];
      }
      const float rr = 1.f / (1.f + __expf(-(gi[0] + gh[0])));
      const float zz = 1.f / (1.f + __expf(-(gi[1] + gh[1])));
      const float nn = tanhf(gi[2] + rr * gh[2]);
      const float h0n = (1.f - zz) * nn + zz * h0c[cb][cj];
      const unsigned long long pk =
          ((unsigned long long)(unsigned)(t + 1) << 32) | (unsigned long long)__float_as_uint(h0n);
      __hip_atomic_store(&h0p[((t + 1) & 1) * 512 + cb * 256 + cj], pk,
                         __ATOMIC_RELAXED, __HIP_MEMORY_SCOPE_AGENT);
    }
    if (tid < 16 && t + 1 < TT) {
#pragma unroll
      for (int g = 0; g < 3; ++g) {
        gihsv[g] = gihs[((long)cb * TT + (t + 1)) * 768 + g*256 + cj];
        piv[g]   = Pm[((long)cb * TT + t) * 768 + g*256 + cj];
      }
    }
    __syncthreads();
    // ---- phase B: h0 exchange hidden under the independent wh1s half
    POLL_ISSUE(h0p + ((t + 1) & 1) * 512, hw);
    if (tfprev) {
      POLL_ISSUE(h1p + (t & 1) * 512, qb);
      POLL_FINISH(h1p + (t & 1) * 512, qb, h1c, t);
      __syncthreads();
    }
    HALF_DOTS(wh1s, h1c, 1);
    POLL_FINISH(h0p + ((t + 1) & 1) * 512, hw, h0c, t + 1);
    __syncthreads();
    HALF_DOTS(wi1s, h0c, 0);
    __syncthreads();
    if (tid < 16) {
      float gi[3], gh[3];
#pragma unroll
      for (int g = 0; g < 3; ++g) {
        gi[g] = dotsS[0][cb][g][cjj] + bi1v[g];
        gh[g] = dotsS[1][cb][g][cjj] + bh1v[g];
      }
      const float rr = 1.f / (1.f + __expf(-(gi[0] + gh[0])));
      const float zz = 1.f / (1.f + __expf(-(gi[1] + gh[1])));
      const float nn = tanhf(gi[2] + rr * gh[2]);
      const float h1n = (1.f - zz) * nn + zz * h1c[cb][cj];
      const unsigned hb = (unsigned)f2bf(h1n);
      asm volatile("global_store_short %0, %1, off sc0 sc1"
                   :: "v"(&h1sb[((long)cb * TT + t) * 256 + cj]), "v"(hb) : "memory");
      const unsigned long long pk =
          ((unsigned long long)(unsigned)(t + 1) << 32) | (unsigned long long)__float_as_uint(h1n);
      __hip_atomic_store(&h1p[((t + 1) & 1) * 512 + cb * 256 + cj], pk,
                         __ATOMIC_RELAXED, __HIP_MEMORY_SCOPE_AGENT);
    }
    if ((t & 15) == 15) {
      if (wave == 0) asm volatile("s_waitcnt vmcnt(0)" ::: "memory");
      if (tid == 0)
        __hip_atomic_store(&prog[wg * 16], (unsigned)(t + 1),
                           __ATOMIC_RELAXED, __HIP_MEMORY_SCOPE_AGENT);
    }
    __syncthreads();
  }
}

__global__ void loss_finalize(const float* __restrict__ lossp, int n, float* __restrict__ out) {
  __shared__ float red[256];
  float s = 0.f;
  for (int i = threadIdx.x; i < n; i += 256) s += lossp[i];
  red[threadIdx.x] = s;
  __syncthreads();
  for (int st = 128; st > 0; st >>= 1) {
    if (threadIdx.x < st) red[threadIdx.x] += red[threadIdx.x + st];
    __syncthreads();
  }
  if (threadIdx.x == 0) out[0] = red[0] * (1.0f / 71792640.0f);
}

// ---------------------------------------------------------------------------
extern "C" void kernel_launch(void* const* d_in, const int* in_sizes, int n_in,
                              void* d_out, int out_size, void* d_ws, size_t ws_size,
                              hipStream_t stream) {
  (void)in_sizes; (void)n_in; (void)out_size;
  const float* hs   = (const float*)d_in[0];
  const float* tmpl = (const float*)d_in[1];
  const float* vert = (const float*)d_in[2];
  const int*   tfm  = (const int*)  d_in[3];
  const float* wih0 = (const float*)d_in[4];
  const float* whh0 = (const float*)d_in[5];
  const float* bih0 = (const float*)d_in[6];
  const float* bhh0 = (const float*)d_in[7];
  const float* wih1 = (const float*)d_in[8];
  const float* whh1 = (const float*)d_in[9];
  const float* bih1 = (const float*)d_in[10];
  const float* bhh1 = (const float*)d_in[11];
  const float* fcw  = (const float*)d_in[12];
  const float* fcb  = (const float*)d_in[13];
  const float* redw = (const float*)d_in[14];
  const float* redb = (const float*)d_in[15];
  float* out = (float*)d_out;

  char* ws = (char*)d_ws;
  float*    LOSSP = (float*)(ws + 0);          // overlaps OUTG (dead after transpose)
  float*    OUTG  = (float*)(ws + 0);          // [768][1024]
  float*    OUTM  = (float*)(ws + 3145728);    // [768][256]
  float*    EXTRA = (float*)(ws + 3932160);    // [3][768]
  unsigned long long* H0P = (unsigned long long*)(ws + 3941376); // [2][512]
  unsigned long long* H1P = (unsigned long long*)(ws + 3949568); // [2][512]
  unsigned* PROG  = (unsigned*)(ws + 3957760); // 32 slots x 16 stride
  float*    GF    = (float*)(ws + 3960064);    // [1027][768]
  float*    MT    = (float*)(ws + 7115776);    // [256][768]
  float*    GIHS  = (float*)(ws + 7902208);    // [1024][768]
  float*    PM    = (float*)(ws + 11047936);   // [1027][768]
  float*    M2    = (float*)(ws + 14203648);   // [768][256]
  unsigned short* H1SB = (unsigned short*)(ws + 14990080); // [1024][256] bf16
  // bf16 staging buffers (gated on ws_size)
  unsigned short* RB = (unsigned short*)(ws + 15514624);   // [768][70144]
  unsigned short* VB = (unsigned short*)(ws + 123255808);  // [1024][70144]
  unsigned short* FB = (unsigned short*)(ws + 266910720);  // [70110][256]
  const size_t NEEDED = 302807040UL;
  const int useBF = (ws_size >= NEEDED) ? 1 : 0;

  // zero split-K accumulators + EXTRA + tag buffers + progress (every call)
  hipMemsetAsync(d_ws, 0, 3960064, stream);

  if (useBF) {
    tobf16<<<dim3(35, 768),  256, 0, stream>>>(redw, RB, VD, VDP, VD, VDP);
    tobf16<<<dim3(35, 1024), 256, 0, stream>>>(vert, VB, VD, VDP, VD, VDP);
    tobf16<<<dim3(8764, 1),  256, 0, stream>>>(fcw,  FB, 17948160L, 17948160L, 17948160, 17948160);
    // 255 blocks (single occupancy round), CHK mult of 32, pad-zero covered
    bigk_bf16<<<dim3(5, 3, 17), 512, 0, stream>>>(RB, VB, FB, OUTG, OUTM, 4128);
  } else {
    bigk_merged<<<dim3(5, 3, 21), 512, 0, stream>>>(redw, vert, fcw, OUTG, OUTM, 3344);
  }
  gemv3<<<dim3(96, 8), 256, 0, stream>>>(redw, tmpl, fcb, EXTRA);

  // merged transposes (+red_b fold) + GF odd-row fixup
  transpose_merged<<<dim3(32, 24, 2), 256, 0, stream>>>(OUTG, OUTM, EXTRA, redb, GF, MT);

  // merged small GEMMs: gihs / PM / M2
  gemm128x3<<<dim3(9, 6, 3), 256, 0, stream>>>(hs, wih0, GIHS, bih0, GF, PM, MT, M2);

  // fused recurrence (32 producer WGs) + fc GEMM/MSE (224 consumer WGs)
  k3_fused<<<256, 512, 0, stream>>>(GIHS, PM, M2, whh0, bhh0, wih1, bih1, whh1, bhh1,
                                    tfm, H1SB, H0P, H1P, PROG,
                                    fcw, FB, useBF, fcb, vert, out, LOSSP);

  loss_finalize<<<1, 256, 0, stream>>>(LOSSP, 4384, out + 71792640L);
}

// Round 13
// 2501.064 us; speedup vs baseline: 1.2533x; 1.2533x over previous
//
#include <hip/hip_runtime.h>
#include <hip/hip_bf16.h>

// ---------------------------------------------------------------------------
// FaceXHuBERT decoder: 2-layer GRU (H=256) over T=512 + fc to V=70110 with
// teacher-forcing feedback through red_w [A=768, V].
//
// Round 13: SPLIT-PIPELINE the bigk->transpose->PM chain by t-range.
//   Stage 1 (prologue): bigk n-blocks {0,2} (t<256 both batches) + OUTM
//     (189 blocks = 1 occupancy round); transpose + PM for those rows only.
//   Stage 2 (inside k3_fused): 126 idle tx=3 consumer WGs compute bigk
//     n-blocks {1,3}; 24 of them chain transpose (OUTG -> bf16 GF2B, agent
//     atomics) -> PM row-blocks {2,3,6,7} (MFMA) -> S2P flag. Producers gate
//     once at iteration 256 (PM rows >=256 not needed earlier).
//   All cross-WG stage-2 data via agent-scope atomics; buffers first-touch.
// Also: revert r12's RB/VB bf16 conversion (net loss); keep fcw->FB bf16 for
// consumers (r12 evidence: k3 FETCH 469->325MB, -75us).
// ---------------------------------------------------------------------------

#define TT 512
#define VD 70110
#define NR 1024

using bf16x8 = __attribute__((ext_vector_type(8))) short;
using f32x4  = __attribute__((ext_vector_type(4))) float;

static __device__ __forceinline__ unsigned short f2bf(float f) {
  unsigned u = __float_as_uint(f);
  u += 0x7FFFu + ((u >> 16) & 1u);   // RNE
  return (unsigned short)(u >> 16);
}

// ---------------- f32 -> bf16 conversion ------------------------------------
__global__ __launch_bounds__(256)
void tobf16(const float* __restrict__ src, unsigned short* __restrict__ dst, long n)
{
  const long c0 = ((long)blockIdx.x * 256 + threadIdx.x) * 8;
  if (c0 + 8 <= n) {
    const float2* s2 = (const float2*)(src + c0);
    unsigned short t[8] __attribute__((aligned(16)));
#pragma unroll
    for (int i = 0; i < 4; ++i) { float2 v = s2[i]; t[2*i] = f2bf(v.x); t[2*i+1] = f2bf(v.y); }
    *(int4*)(dst + c0) = *(int4*)t;
  } else {
    for (long c = c0; c < n; ++c) dst[c] = f2bf(src[c]);
  }
}

// ---------------- merged big split-K GEMM over V (bf16 MFMA, atomicAdd) -----
// xmap=1: blockIdx.x in {0,1,2} -> x {0,2,4}  (stage-1: n-blocks 0,2 + OUTM)
// xmap=0: identity (full, fallback)
__global__ __launch_bounds__(512, 1)
void bigk_merged(const float* __restrict__ A, const float* __restrict__ vert,
                 const float* __restrict__ fcw,
                 float* __restrict__ OUTG, float* __restrict__ OUTM, int CHK, int xmap)
{
  __shared__ unsigned short Al[256][40];
  __shared__ unsigned short Bl[256][40];
  const int tid = threadIdx.x;
  const int xs3[3] = {0, 2, 4};
  const int x = xmap ? xs3[blockIdx.x] : blockIdx.x;
  const bool bform = (x == 4);
  float* C      = bform ? OUTM : OUTG;
  const int ldc = bform ? 256 : 1024;
  const int N   = bform ? 256 : 1024;
  const int n0  = bform ? 0 : x * 256;
  const int m0  = blockIdx.y * 256;
  const int kc0 = blockIdx.z * CHK;
  const int kc1 = min(VD, kc0 + CHK);
  const int wave = tid >> 6, lane = tid & 63;
  const int wm = wave >> 1, wn = wave & 1;
  const int kq = lane >> 4, ln = lane & 15;
  f32x4 acc[4][8] = {};
  for (int kc = kc0; kc < kc1; kc += 32) {
    __syncthreads();
    {
      const int m = tid >> 1, kh = (tid & 1) << 4;
      const float* arow = A + (long)(m0 + m) * (long)VD;
      unsigned short tmp[16] __attribute__((aligned(16)));
      if (kc + 32 <= kc1) {
        const float2* ap2 = (const float2*)(arow + kc + kh);
#pragma unroll
        for (int i = 0; i < 8; ++i) { float2 v = ap2[i]; tmp[2*i] = f2bf(v.x); tmp[2*i+1] = f2bf(v.y); }
      } else {
#pragma unroll
        for (int i = 0; i < 16; ++i) {
          int kk = kc + kh + i;
          tmp[i] = f2bf((kk < kc1) ? arow[kk] : 0.f);
        }
      }
      ((int4*)&Al[m][kh])[0] = *(int4*)&tmp[0];
      ((int4*)&Al[m][kh])[1] = *(int4*)&tmp[8];
    }
    if (!bform) {
      const int n = tid >> 1, kh = (tid & 1) << 4;
      const float* bp = vert + (long)(n0 + n) * (long)VD;
      unsigned short tmp[16] __attribute__((aligned(16)));
      if (kc + 32 <= kc1) {
        const float2* bp2 = (const float2*)(bp + kc + kh);
#pragma unroll
        for (int i = 0; i < 8; ++i) { float2 v = bp2[i]; tmp[2*i] = f2bf(v.x); tmp[2*i+1] = f2bf(v.y); }
      } else {
#pragma unroll
        for (int i = 0; i < 16; ++i) {
          int kk = kc + kh + i;
          tmp[i] = f2bf((kk < kc1) ? bp[kk] : 0.f);
        }
      }
      ((int4*)&Bl[n][kh])[0] = *(int4*)&tmp[0];
      ((int4*)&Bl[n][kh])[1] = *(int4*)&tmp[8];
    } else {
      const int n = tid & 255, kh = (tid >> 8) << 4;
      unsigned short tmp[16] __attribute__((aligned(16)));
#pragma unroll
      for (int i = 0; i < 16; ++i) {
        int kk = kc + kh + i;
        float v = 0.f;
        if (kk < kc1 && n < 256) v = fcw[(long)kk * 256 + n];
        tmp[i] = f2bf(v);
      }
      ((int4*)&Bl[n][kh])[0] = *(int4*)&tmp[0];
      ((int4*)&Bl[n][kh])[1] = *(int4*)&tmp[8];
    }
    __syncthreads();
    bf16x8 af[4], bfv[8];
#pragma unroll
    for (int i = 0; i < 4; ++i) af[i] = *(const bf16x8*)&Al[wm*64 + i*16 + ln][kq*8];
#pragma unroll
    for (int j = 0; j < 8; ++j) bfv[j] = *(const bf16x8*)&Bl[wn*128 + j*16 + ln][kq*8];
#pragma unroll
    for (int i = 0; i < 4; ++i)
#pragma unroll
      for (int j = 0; j < 8; ++j)
        acc[i][j] = __builtin_amdgcn_mfma_f32_16x16x32_bf16(af[i], bfv[j], acc[i][j], 0, 0, 0);
  }
#pragma unroll
  for (int i = 0; i < 4; ++i)
#pragma unroll
    for (int j = 0; j < 8; ++j)
#pragma unroll
      for (int r = 0; r < 4; ++r) {
        int gm = m0 + wm*64 + i*16 + kq*4 + r;
        int gn = n0 + wn*128 + j*16 + ln;
        if (gn < N) unsafeAtomicAdd(&C[(long)gm * ldc + gn], acc[i][j][r]);
      }
}

// ---------------- gemv3 -----------------------------------------------------
__global__ __launch_bounds__(256)
void gemv3(const float* __restrict__ redw, const float* __restrict__ tmpl,
           const float* __restrict__ fcb, float* __restrict__ extra)
{
  const int tid = threadIdx.x;
  const int a0 = blockIdx.x * 8;
  const long k0 = (long)blockIdx.y * 8764;
  const long k1 = (k0 + 8764 < (long)VD) ? (k0 + 8764) : (long)VD;
  float s[3][8] = {};
  for (long k = k0 + tid; k < k1; k += 256) {
    const float c0 = tmpl[k], c1 = tmpl[(long)VD + k], cb2 = fcb[k];
#pragma unroll
    for (int r = 0; r < 8; ++r) {
      const float w = redw[(long)(a0 + r) * VD + k];
      s[0][r] += c0 * w; s[1][r] += c1 * w; s[2][r] += cb2 * w;
    }
  }
#pragma unroll
  for (int v = 0; v < 3; ++v)
#pragma unroll
    for (int r = 0; r < 8; ++r) {
      float x = s[v][r];
#pragma unroll
      for (int o = 32; o > 0; o >>= 1) x += __shfl_down(x, o);
      if ((tid & 63) == 0) unsafeAtomicAdd(&extra[v * 768 + a0 + r], x);
    }
}

// ---------------- merged transposes (+red_b) + fixup ------------------------
static __device__ __forceinline__ void transpose_body(
    const float* src, int lds, float* dst, int ldd,
    int rows, int cols, const float* bias, int bx, int by)
{
  __shared__ float tile[32][33];
  const int rb = bx * 32, cb = by * 32;
  const int tx = threadIdx.x & 31, ty = threadIdx.x >> 5;
  for (int yy = ty; yy < 32; yy += 8) {
    int c = cb + yy, r = rb + tx;
    tile[yy][tx] = (c < cols && r < rows) ? src[(long)c * lds + r] : 0.f;
  }
  __syncthreads();
  for (int yy = ty; yy < 32; yy += 8) {
    int r = rb + yy, c = cb + tx;
    if (r < rows && c < cols)
      dst[(long)r * ldd + c] = tile[tx][yy] + (bias ? bias[c] : 0.f);
  }
}

__global__ void transpose_merged(const float* __restrict__ OUTG,
                                 const float* __restrict__ OUTM,
                                 const float* __restrict__ extra,
                                 const float* __restrict__ redb,
                                 float* __restrict__ GF, float* __restrict__ MT,
                                 int s2on)
{
  if (blockIdx.z == 0) {
    int bx = blockIdx.x;
    if (s2on) {                 // stage-1 only rows 0-255 and 512-767
      if (bx >= 16) return;
      bx = (bx < 8) ? bx : bx + 8;
    }
    transpose_body(OUTG, 1024, GF, 768, 1024, 768, redb, bx, blockIdx.y);
  } else {
    if (blockIdx.x < 8) {
      transpose_body(OUTM, 256, MT, 768, 256, 768, nullptr, blockIdx.x, blockIdx.y);
    } else if (blockIdx.x == 8 && blockIdx.y == 0) {
      for (int i = threadIdx.x; i < 3 * 768; i += 256) {
        const int b = i / 768, a = i - b * 768;
        GF[(long)(1024 + b) * 768 + a] = extra[i] + redb[a];
      }
    }
  }
}

// ---------------- merged small GEMMs (gihs / PM-stage1 / M2) ----------------
__global__ __launch_bounds__(256, 2)
void gemm128x3(const float* __restrict__ hs, const float* __restrict__ wih0,
               float* __restrict__ GIHS, const float* __restrict__ bih0,
               const float* __restrict__ GF, float* __restrict__ PM,
               const float* __restrict__ MT, float* __restrict__ M2, int s2on)
{
  const float *A, *B, *bias = nullptr; float* C;
  int lda, ldb, M, N, K; long ldc; int mblk = blockIdx.x;
  if (blockIdx.z == 0) {
    if (blockIdx.x >= 8) return;
    A = hs; lda = 768; B = wih0; ldb = 1536; C = GIHS; ldc = 768; bias = bih0;
    M = 1024; N = 768; K = 768;
  } else if (blockIdx.z == 1) {
    if (s2on) {               // stage-1 PM row blocks {0,1,4,5,8}
      const int tbl[5] = {0, 1, 4, 5, 8};
      if (blockIdx.x >= 5) return;
      mblk = tbl[blockIdx.x];
    }
    A = GF; lda = 768; B = wih0 + 768; ldb = 1536; C = PM; ldc = 768;
    M = 1027; N = 768; K = 768;
  } else {
    if (blockIdx.x >= 6 || blockIdx.y >= 2) return;
    A = wih0 + 768; lda = 1536; B = MT; ldb = 768; C = M2; ldc = 256;
    M = 768; N = 256; K = 768;
  }
  __shared__ unsigned short Al[128][40];
  __shared__ unsigned short Bl[128][40];
  const int tid = threadIdx.x;
  const int m0 = mblk * 128, n0 = blockIdx.y * 128;
  const int wave = tid >> 6, lane = tid & 63;
  const int wm = wave >> 1, wn = wave & 1;
  const int kq = lane >> 4, ln = lane & 15;
  f32x4 acc[4][4] = {};
  for (int kc = 0; kc < K; kc += 32) {
    __syncthreads();
    {
      const int m = tid >> 1, kh = (tid & 1) << 4;
      unsigned short tmp[16] __attribute__((aligned(16)));
      const bool mok = (m0 + m) < M;
      if (mok) {
        const float4* ap4 = (const float4*)(A + (long)(m0 + m) * lda + kc + kh);
#pragma unroll
        for (int i = 0; i < 4; ++i) {
          float4 v = ap4[i];
          tmp[4*i+0] = f2bf(v.x); tmp[4*i+1] = f2bf(v.y);
          tmp[4*i+2] = f2bf(v.z); tmp[4*i+3] = f2bf(v.w);
        }
      } else {
#pragma unroll
        for (int i = 0; i < 16; ++i) tmp[i] = 0;
      }
      ((int4*)&Al[m][kh])[0] = *(int4*)&tmp[0];
      ((int4*)&Al[m][kh])[1] = *(int4*)&tmp[8];
      const int n = m;
      unsigned short tmb[16] __attribute__((aligned(16)));
      const bool nok = (n0 + n) < N;
      if (nok) {
        const float4* bp4 = (const float4*)(B + (long)(n0 + n) * ldb + kc + kh);
#pragma unroll
        for (int i = 0; i < 4; ++i) {
          float4 v = bp4[i];
          tmb[4*i+0] = f2bf(v.x); tmb[4*i+1] = f2bf(v.y);
          tmb[4*i+2] = f2bf(v.z); tmb[4*i+3] = f2bf(v.w);
        }
      } else {
#pragma unroll
        for (int i = 0; i < 16; ++i) tmb[i] = 0;
      }
      ((int4*)&Bl[n][kh])[0] = *(int4*)&tmb[0];
      ((int4*)&Bl[n][kh])[1] = *(int4*)&tmb[8];
    }
    __syncthreads();
    bf16x8 af[4], bfv[4];
#pragma unroll
    for (int i = 0; i < 4; ++i) af[i]  = *(const bf16x8*)&Al[wm*64 + i*16 + ln][kq*8];
#pragma unroll
    for (int j = 0; j < 4; ++j) bfv[j] = *(const bf16x8*)&Bl[wn*64 + j*16 + ln][kq*8];
#pragma unroll
    for (int i = 0; i < 4; ++i)
#pragma unroll
      for (int j = 0; j < 4; ++j)
        acc[i][j] = __builtin_amdgcn_mfma_f32_16x16x32_bf16(af[i], bfv[j], acc[i][j], 0, 0, 0);
  }
#pragma unroll
  for (int i = 0; i < 4; ++i)
#pragma unroll
    for (int j = 0; j < 4; ++j)
#pragma unroll
      for (int r = 0; r < 4; ++r) {
        const int gm = m0 + wm*64 + i*16 + kq*4 + r;
        const int gn = n0 + wn*64 + j*16 + ln;
        if (gm < M && gn < N) {
          float v = acc[i][j][r];
          if (bias) v += bias[gn];
          C[(long)gm * ldc + gn] = v;
        }
      }
}

// ---------------- fused recurrence + fc GEMM + stage-2 ----------------------
struct ProdLds {
  float wq[24][260], wh0s[24][260], wi1s[24][260], wh1s[24][260];
  float h0c[2][256], h1c[2][256];
  float dotsS[2][2][3][8];
  int tfl[TT];
};
struct ConsLds {
  unsigned short As[128][264];
  unsigned short Bl[128][40];
  float wred[8];
};
struct S2Lds {
  unsigned short Al[256][40];
  unsigned short Bl[256][40];
};

#define HALF_DOTS(W, H, MS)                                                   \
  {                                                                           \
    const int g8_ = tid >> 3, l8_ = tid & 7;                                  \
    if (g8_ < 48) {                                                           \
      const int row_ = g8_ >> 1, bb_ = g8_ & 1;                               \
      const float4* w4_ = (const float4*)&(W)[row_][0];                       \
      const float4* h4_ = (const float4*)&(H)[bb_][0];                        \
      float s_ = 0.f;                                                         \
      _Pragma("unroll")                                                       \
      for (int i = 0; i < 8; ++i) {                                           \
        const float4 a_ = w4_[i * 8 + l8_], h_ = h4_[i * 8 + l8_];            \
        s_ += a_.x * h_.x + a_.y * h_.y + a_.z * h_.z + a_.w * h_.w;          \
      }                                                                       \
      s_ += __shfl_xor(s_, 1); s_ += __shfl_xor(s_, 2); s_ += __shfl_xor(s_, 4); \
      if (l8_ == 0) dotsS[MS][bb_][row_ >> 3][row_ & 7] = s_;                 \
    }                                                                         \
  }

#define POLL_ISSUE(buf, var)                                                  \
  unsigned long long var = __hip_atomic_load(&(buf)[tid], __ATOMIC_RELAXED, __HIP_MEMORY_SCOPE_AGENT);
#define POLL_FINISH(buf, var, dstLds, want)                                   \
  {                                                                           \
    const unsigned w_ = (unsigned)(want); int sp_ = 0;                        \
    while ((unsigned)(var >> 32) < w_ && ++sp_ < (1 << 15)) {                 \
      __builtin_amdgcn_s_sleep(1);                                            \
      var = __hip_atomic_load(&(buf)[tid], __ATOMIC_RELAXED, __HIP_MEMORY_SCOPE_AGENT); \
    }                                                                         \
    ((float*)dstLds)[tid] = __uint_as_float((unsigned)var);                   \
  }
#define POLLP(buf, dstLds, want)                                              \
  { POLL_ISSUE(buf, pw_); POLL_FINISH(buf, pw_, dstLds, want); }

__global__ __launch_bounds__(512, 1)
void k3_fused(const float* __restrict__ gihs, const float* Pm,
              const float* __restrict__ M2m,
              const float* __restrict__ whh0, const float* __restrict__ bhh0,
              const float* __restrict__ wih1, const float* __restrict__ bih1,
              const float* __restrict__ whh1, const float* __restrict__ bhh1,
              const int* __restrict__ tfm,
              unsigned short* __restrict__ h1sb,
              unsigned long long* __restrict__ h0p, unsigned long long* __restrict__ h1p,
              unsigned* __restrict__ prog,
              const float* __restrict__ fcw, const unsigned short* __restrict__ FB,
              int s2on,
              const float* __restrict__ fcb, const float* __restrict__ vert,
              float* __restrict__ out, float* __restrict__ lossp,
              const float* __restrict__ redw, float* __restrict__ outg,
              unsigned short* __restrict__ gf2b, float* pmw,
              const float* __restrict__ redb, const float* __restrict__ wr)
{
  __shared__ union { ProdLds p; ConsLds c; S2Lds s; } U;
  const int tid = threadIdx.x;

  if (blockIdx.x >= 32) {
    const int idx = blockIdx.x - 32;

    // ================= STAGE 2 (126 of the tx=3 WGs) =======================
    if (s2on && idx >= 96 && idx < 222) {
      const int r2 = idx - 96;           // 0..125
      { // ---- one bigk block for n-blocks {1,3} (f32 staging path) ---------
        auto& S = U.s;
        const int x2 = (r2 < 63) ? 1 : 3;
        const int rem = (r2 < 63) ? r2 : r2 - 63;
        const int m0 = (rem / 21) * 256;
        const int kc0 = (rem % 21) * 3344;
        const int kc1 = min(VD, kc0 + 3344);
        const int n0 = x2 * 256;
        const int wave = tid >> 6, lane = tid & 63;
        const int wm = wave >> 1, wn = wave & 1;
        const int kq = lane >> 4, ln = lane & 15;
        f32x4 acc[4][8] = {};
        for (int kc = kc0; kc < kc1; kc += 32) {
          __syncthreads();
          {
            const int m = tid >> 1, kh = (tid & 1) << 4;
            const float* arow = redw + (long)(m0 + m) * (long)VD;
            unsigned short tmp[16] __attribute__((aligned(16)));
            if (kc + 32 <= kc1) {
              const float2* ap2 = (const float2*)(arow + kc + kh);
#pragma unroll
              for (int i = 0; i < 8; ++i) { float2 v = ap2[i]; tmp[2*i] = f2bf(v.x); tmp[2*i+1] = f2bf(v.y); }
            } else {
#pragma unroll
              for (int i = 0; i < 16; ++i) {
                int kk = kc + kh + i;
                tmp[i] = f2bf((kk < kc1) ? arow[kk] : 0.f);
              }
            }
            ((int4*)&S.Al[m][kh])[0] = *(int4*)&tmp[0];
            ((int4*)&S.Al[m][kh])[1] = *(int4*)&tmp[8];
            const float* bp = vert + (long)(n0 + m) * (long)VD;
            unsigned short tmb[16] __attribute__((aligned(16)));
            if (kc + 32 <= kc1) {
              const float2* bp2 = (const float2*)(bp + kc + kh);
#pragma unroll
              for (int i = 0; i < 8; ++i) { float2 v = bp2[i]; tmb[2*i] = f2bf(v.x); tmb[2*i+1] = f2bf(v.y); }
            } else {
#pragma unroll
              for (int i = 0; i < 16; ++i) {
                int kk = kc + kh + i;
                tmb[i] = f2bf((kk < kc1) ? bp[kk] : 0.f);
              }
            }
            ((int4*)&S.Bl[m][kh])[0] = *(int4*)&tmb[0];
            ((int4*)&S.Bl[m][kh])[1] = *(int4*)&tmb[8];
          }
          __syncthreads();
          bf16x8 af[4], bfv[8];
#pragma unroll
          for (int i = 0; i < 4; ++i) af[i] = *(const bf16x8*)&S.Al[wm*64 + i*16 + ln][kq*8];
#pragma unroll
          for (int j = 0; j < 8; ++j) bfv[j] = *(const bf16x8*)&S.Bl[wn*128 + j*16 + ln][kq*8];
#pragma unroll
          for (int i = 0; i < 4; ++i)
#pragma unroll
            for (int j = 0; j < 8; ++j)
              acc[i][j] = __builtin_amdgcn_mfma_f32_16x16x32_bf16(af[i], bfv[j], acc[i][j], 0, 0, 0);
        }
#pragma unroll
        for (int i = 0; i < 4; ++i)
#pragma unroll
          for (int j = 0; j < 8; ++j)
#pragma unroll
            for (int r = 0; r < 4; ++r) {
              const int gm = m0 + wm*64 + i*16 + kq*4 + r;
              const int gn = n0 + wn*128 + j*16 + ln;
              unsafeAtomicAdd(&outg[(long)gm * 1024 + gn], acc[i][j][r]);
            }
        __syncthreads();
        if (tid == 0)
          (void)__hip_atomic_fetch_add(&prog[512], 1u, __ATOMIC_RELAXED, __HIP_MEMORY_SCOPE_AGENT);
      }
      if (r2 < 24) {
        // ---- wait all 126 bigk blocks, then transpose OUTG->GF2B (bf16) ----
        if (tid == 0) {
          int sp = 0;
          while (__hip_atomic_load(&prog[512], __ATOMIC_RELAXED, __HIP_MEMORY_SCOPE_AGENT) < 126u) {
            if (++sp > (1 << 16)) break;
            for (int j = 0; j < 8; ++j) __builtin_amdgcn_s_sleep(15);
          }
        }
        __syncthreads();
        const int yy = tid >> 4, pr = tid & 15;
        for (int i = 0; i < 16; ++i) {
          const int tt = r2 * 16 + i;               // 0..383
          const int bxI = tt / 24, by = tt % 24;
          const int bx = (bxI < 8) ? (8 + bxI) : (16 + bxI);   // rows 256-511, 768-1023
          const int r = bx * 32 + yy;
          const int c = by * 32 + pr * 2;
          float f0 = __hip_atomic_load(&outg[(long)c * 1024 + r],
                                       __ATOMIC_RELAXED, __HIP_MEMORY_SCOPE_AGENT);
          float f1 = __hip_atomic_load(&outg[(long)(c + 1) * 1024 + r],
                                       __ATOMIC_RELAXED, __HIP_MEMORY_SCOPE_AGENT);
          const unsigned pk = (unsigned)f2bf(f0 + redb[c]) |
                              ((unsigned)f2bf(f1 + redb[c + 1]) << 16);
          __hip_atomic_store((unsigned*)gf2b + ((long)r * 384 + (c >> 1)), pk,
                             __ATOMIC_RELAXED, __HIP_MEMORY_SCOPE_AGENT);
        }
        if (tid == 0)
          (void)__hip_atomic_fetch_add(&prog[520], 1u, __ATOMIC_RELAXED, __HIP_MEMORY_SCOPE_AGENT);
        if (tid == 0) {
          int sp = 0;
          while (__hip_atomic_load(&prog[520], __ATOMIC_RELAXED, __HIP_MEMORY_SCOPE_AGENT) < 24u) {
            if (++sp > (1 << 16)) break;
            for (int j = 0; j < 4; ++j) __builtin_amdgcn_s_sleep(15);
          }
        }
        __syncthreads();
        // ---- one 128x128 PM tile (row blocks {2,3,6,7} x 6 col blocks) ----
        {
          auto& S = U.s;
          unsigned short (*Als)[40] = (unsigned short(*)[40])&S.Al[0][0];
          unsigned short (*Bls)[40] = (unsigned short(*)[40])&S.Bl[0][0];
          const int rowtbl[4] = {2, 3, 6, 7};
          const int m0 = rowtbl[r2 / 6] * 128;
          const int n0 = (r2 % 6) * 128;
          const int wave = tid >> 6, lane = tid & 63;
          const int wm = wave >> 2, wn = wave & 3;
          const int kq = lane >> 4, ln = lane & 15;
          f32x4 acc[4][2] = {};
          for (int kc = 0; kc < 768; kc += 32) {
            __syncthreads();
            {
              const unsigned* g2 = (const unsigned*)gf2b;
#pragma unroll
              for (int i = 0; i < 4; ++i) {
                const int u = tid * 4 + i;          // 0..2047
                const int row = u >> 4, cp = u & 15;
                unsigned v = __hip_atomic_load(&g2[(long)(m0 + row) * 384 + (kc >> 1) + cp],
                                               __ATOMIC_RELAXED, __HIP_MEMORY_SCOPE_AGENT);
                *(unsigned*)&Als[row][cp * 2] = v;
              }
#pragma unroll
              for (int i = 0; i < 4; ++i) {
                const int u = tid * 4 + i;
                const int row = u >> 4, k2 = (u & 15) * 2;
                const float2 v = *(const float2*)&wr[(long)(n0 + row) * 1536 + kc + k2];
                const unsigned pk = (unsigned)f2bf(v.x) | ((unsigned)f2bf(v.y) << 16);
                *(unsigned*)&Bls[row][k2] = pk;
              }
            }
            __syncthreads();
            bf16x8 af[4], bfv[2];
#pragma unroll
            for (int i = 0; i < 4; ++i)
              af[i] = *(const bf16x8*)&Als[wm*64 + i*16 + ln][kq*8];
#pragma unroll
            for (int j = 0; j < 2; ++j)
              bfv[j] = *(const bf16x8*)&Bls[wn*32 + j*16 + ln][kq*8];
#pragma unroll
            for (int i = 0; i < 4; ++i)
#pragma unroll
              for (int j = 0; j < 2; ++j)
                acc[i][j] = __builtin_amdgcn_mfma_f32_16x16x32_bf16(af[i], bfv[j], acc[i][j], 0, 0, 0);
          }
#pragma unroll
          for (int i = 0; i < 4; ++i)
#pragma unroll
            for (int j = 0; j < 2; ++j)
#pragma unroll
              for (int r = 0; r < 4; ++r) {
                const int gm = m0 + wm*64 + i*16 + kq*4 + r;
                const int gn = n0 + wn*32 + j*16 + ln;
                __hip_atomic_store(&pmw[(long)gm * 768 + gn], acc[i][j][r],
                                   __ATOMIC_RELAXED, __HIP_MEMORY_SCOPE_AGENT);
              }
        }
        __syncthreads();
        if (tid == 0)
          (void)__hip_atomic_fetch_add(&prog[528], 1u, __ATOMIC_RELAXED, __HIP_MEMORY_SCOPE_AGENT);
      }
      __syncthreads();
    }

    // ================= CONSUMER: fc GEMM tile sweep ========================
    auto& C = U.c;
    int tx, memb, cnt;
    if (idx < 24)      { tx = 0; memb = (idx)      >> 1; cnt = 12; }
    else if (idx < 48) { tx = 1; memb = (idx - 24) >> 1; cnt = 12; }
    else if (idx < 96) { tx = 2; memb = (idx - 48) >> 1; cnt = 24; }
    else               { tx = 3; memb = (idx - 96) >> 1; cnt = 64; }
    const int b = idx & 1;
    const int nt0 = memb * 548 / cnt, nt1 = (memb + 1) * 548 / cnt;
    if (nt0 >= nt1) return;
    const unsigned want = (unsigned)((tx + 1) * 128);
    if (tid < 32) {
      int sp = 0;
      while (__hip_atomic_load(&prog[tid * 16], __ATOMIC_RELAXED, __HIP_MEMORY_SCOPE_AGENT) < want) {
        if (++sp > (1 << 14)) break;
        for (int j = 0; j < 16; ++j) __builtin_amdgcn_s_sleep(15);
      }
    }
    __syncthreads();
    const long rbase = (long)b * 512 + (long)tx * 128;
    {
      const unsigned long long* src = (const unsigned long long*)(h1sb + rbase * 256);
#pragma unroll
      for (int i = 0; i < 16; ++i) {
        const int u = tid * 16 + i;
        unsigned long long v = __hip_atomic_load(&src[u], __ATOMIC_RELAXED, __HIP_MEMORY_SCOPE_AGENT);
        const int row = u >> 6, c4 = u & 63;
        *(unsigned long long*)&C.As[row][c4 * 4] = v;
      }
    }
    __syncthreads();
    const int wave = tid >> 6, lane = tid & 63;
    const int wm = wave >> 2, wn = wave & 3;
    const int kq = lane >> 4, ln = lane & 15;
    for (int nt = nt0; nt < nt1; ++nt) {
      const int n0 = nt * 128;
      f32x4 acc[4][2] = {};
#pragma unroll 1
      for (int ks = 0; ks < 8; ++ks) {
        __syncthreads();
        {
          const int rn = tid >> 2, kh = (tid & 3) * 8;
          const int gn = n0 + rn;
          if (s2on) {
            int4 v = {0, 0, 0, 0};
            if (gn < VD) v = *(const int4*)(FB + (long)gn * 256 + ks * 32 + kh);
            *(int4*)&C.Bl[rn][kh] = v;
          } else {
            unsigned short tmb[8] __attribute__((aligned(16)));
            if (gn < VD) {
              const float4* bp = (const float4*)&fcw[(long)gn * 256 + ks * 32 + kh];
              float4 v0 = bp[0], v1 = bp[1];
              tmb[0] = f2bf(v0.x); tmb[1] = f2bf(v0.y); tmb[2] = f2bf(v0.z); tmb[3] = f2bf(v0.w);
              tmb[4] = f2bf(v1.x); tmb[5] = f2bf(v1.y); tmb[6] = f2bf(v1.z); tmb[7] = f2bf(v1.w);
            } else {
#pragma unroll
              for (int i = 0; i < 8; ++i) tmb[i] = 0;
            }
            *(int4*)&C.Bl[rn][kh] = *(int4*)tmb;
          }
        }
        __syncthreads();
        bf16x8 af[4], bfv[2];
#pragma unroll
        for (int i = 0; i < 4; ++i)
          af[i] = *(const bf16x8*)&C.As[wm*64 + i*16 + ln][ks*32 + kq*8];
#pragma unroll
        for (int j = 0; j < 2; ++j)
          bfv[j] = *(const bf16x8*)&C.Bl[wn*32 + j*16 + ln][kq*8];
#pragma unroll
        for (int i = 0; i < 4; ++i)
#pragma unroll
          for (int j = 0; j < 2; ++j)
            acc[i][j] = __builtin_amdgcn_mfma_f32_16x16x32_bf16(af[i], bfv[j], acc[i][j], 0, 0, 0);
      }
      float ls = 0.f;
#pragma unroll
      for (int i = 0; i < 4; ++i)
#pragma unroll
        for (int j = 0; j < 2; ++j)
#pragma unroll
          for (int r = 0; r < 4; ++r) {
            const int gmL = wm*64 + i*16 + kq*4 + r;
            const int gn = n0 + wn*32 + j*16 + ln;
            if (gn < VD) {
              const float v = acc[i][j][r] + fcb[gn];
              const long grow = rbase + gmL;
              out[grow * VD + gn] = v;
              const float dd = v - vert[grow * VD + gn];
              ls += dd * dd;
            }
          }
#pragma unroll
      for (int o = 32; o > 0; o >>= 1) ls += __shfl_down(ls, o);
      if (lane == 0) C.wred[wave] = ls;
      __syncthreads();
      if (tid == 0) {
        float s = 0.f;
#pragma unroll
        for (int w = 0; w < 8; ++w) s += C.wred[w];
        lossp[(tx * 2 + b) * 548 + nt] = s;
      }
      __syncthreads();
    }
    return;
  }

  // ================= PRODUCER: round-10 schedule + stage-2 gate ============
  float (&wq)[24][260]   = U.p.wq;
  float (&wh0s)[24][260] = U.p.wh0s;
  float (&wi1s)[24][260] = U.p.wi1s;
  float (&wh1s)[24][260] = U.p.wh1s;
  float (&h0c)[2][256]   = U.p.h0c;
  float (&h1c)[2][256]   = U.p.h1c;
  float (&dotsS)[2][2][3][8] = U.p.dotsS;
  int   (&tfl)[TT]       = U.p.tfl;
  const int wg = blockIdx.x;
  const int j0 = wg * 8;

  {
    const int col = tid & 255, rh = tid >> 8;
    for (int row = rh; row < 24; row += 2) {
      const int g = row >> 3, jj = row & 7;
      const long gr = g * 256 + j0 + jj;
      wq[row][col]   = M2m[gr * 256 + col];
      wh0s[row][col] = whh0[gr * 256 + col];
      wi1s[row][col] = wih1[gr * 256 + col];
      wh1s[row][col] = whh1[gr * 256 + col];
    }
  }
  ((float*)h0c)[tid] = 0.f;
  ((float*)h1c)[tid] = 0.f;
  if (tid < TT) tfl[tid] = tfm[tid];

  const int cb = tid >> 3, cjj = tid & 7, cj = j0 + cjj;
  float bh0v[3], bi1v[3], bh1v[3], d2v[3];
  if (tid < 16) {
#pragma unroll
    for (int g = 0; g < 3; ++g) {
      bh0v[g] = bhh0[g*256 + cj];
      bi1v[g] = bih1[g*256 + cj];
      bh1v[g] = bhh1[g*256 + cj];
      d2v[g]  = Pm[(long)1026 * 768 + g*256 + cj];
    }
  }
  __syncthreads();

  const int wave = tid >> 6;
  float gihsv[3], piv[3];
  if (tid < 16) {
#pragma unroll
    for (int g = 0; g < 3; ++g) {
      gihsv[g] = gihs[((long)cb * TT) * 768 + g*256 + cj];
      piv[g]   = Pm[(long)(1024 + cb) * 768 + g*256 + cj];
    }
  }
  for (int t = 0; t < TT; ++t) {
    if (s2on && t == 256) {     // PM rows >=256 become readable only now
      if (tid == 0) {
        int sp = 0;
        while (__hip_atomic_load(&prog[528], __ATOMIC_RELAXED, __HIP_MEMORY_SCOPE_AGENT) < 24u) {
          if (++sp > (1 << 18)) break;
          __builtin_amdgcn_s_sleep(8);
        }
      }
      __syncthreads();
    }
    const int tfprev = (t == 0) ? 1 : tfl[t - 1];
    // ---- phase A
    if (!tfprev) {
      POLL_ISSUE(h1p + (t & 1) * 512, pb);
      HALF_DOTS(wh0s, h0c, 1);
      POLL_FINISH(h1p + (t & 1) * 512, pb, h1c, t);
      __syncthreads();
      HALF_DOTS(wq, h1c, 0);
    } else {
      HALF_DOTS(wh0s, h0c, 1);
    }
    __syncthreads();
    if (tid < 16) {
      float gi[3], gh[3];
#pragma unroll
      for (int g = 0; g < 3; ++g) {
        const float q = tfprev ? 0.f : (dotsS[0][cb][g][cjj] + d2v[g]);
        gi[g] = gihsv[g] + (tfprev ? piv[g] : q);
        gh[g] = dotsS[1][cb][g][cjj] + bh0v[g];
      }
      const float rr = 1.f / (1.f + __expf(-(gi[0] + gh[0])));
      const float zz = 1.f / (1.f + __expf(-(gi[1] + gh[1])));
      const float nn = tanhf(gi[2] + rr * gh[2]);
      const float h0n = (1.f - zz) * nn + zz * h0c[cb][cj];
      const unsigned long long pk =
          ((unsigned long long)(unsigned)(t + 1) << 32) | (unsigned long long)__float_as_uint(h0n);
      __hip_atomic_store(&h0p[((t + 1) & 1) * 512 + cb * 256 + cj], pk,
                         __ATOMIC_RELAXED, __HIP_MEMORY_SCOPE_AGENT);
    }
    if (tid < 16 && t + 1 < TT) {
#pragma unroll
      for (int g = 0; g < 3; ++g) {
        gihsv[g] = gihs[((long)cb * TT + (t + 1)) * 768 + g*256 + cj];
        piv[g]   = Pm[((long)cb * TT + t) * 768 + g*256 + cj];
      }
    }
    __syncthreads();
    // ---- phase B: h0 exchange hidden under the independent wh1s half
    POLL_ISSUE(h0p + ((t + 1) & 1) * 512, hw);
    if (tfprev) {
      POLL_ISSUE(h1p + (t & 1) * 512, qb);
      POLL_FINISH(h1p + (t & 1) * 512, qb, h1c, t);
      __syncthreads();
    }
    HALF_DOTS(wh1s, h1c, 1);
    POLL_FINISH(h0p + ((t + 1) & 1) * 512, hw, h0c, t + 1);
    __syncthreads();
    HALF_DOTS(wi1s, h0c, 0);
    __syncthreads();
    if (tid < 16) {
      float gi[3], gh[3];
#pragma unroll
      for (int g = 0; g < 3; ++g) {
        gi[g] = dotsS[0][cb][g][cjj] + bi1v[g];
        gh[g] = dotsS[1][cb][g][cjj] + bh1v[g];
      }
      const float rr = 1.f / (1.f + __expf(-(gi[0] + gh[0])));
      const float zz = 1.f / (1.f + __expf(-(gi[1] + gh[1])));
      const float nn = tanhf(gi[2] + rr * gh[2]);
      const float h1n = (1.f - zz) * nn + zz * h1c[cb][cj];
      const unsigned hb = (unsigned)f2bf(h1n);
      asm volatile("global_store_short %0, %1, off sc0 sc1"
                   :: "v"(&h1sb[((long)cb * TT + t) * 256 + cj]), "v"(hb) : "memory");
      const unsigned long long pk =
          ((unsigned long long)(unsigned)(t + 1) << 32) | (unsigned long long)__float_as_uint(h1n);
      __hip_atomic_store(&h1p[((t + 1) & 1) * 512 + cb * 256 + cj], pk,
                         __ATOMIC_RELAXED, __HIP_MEMORY_SCOPE_AGENT);
    }
    if ((t & 15) == 15) {
      if (wave == 0) asm volatile("s_waitcnt vmcnt(0)" ::: "memory");
      if (tid == 0)
        __hip_atomic_store(&prog[wg * 16], (unsigned)(t + 1),
                           __ATOMIC_RELAXED, __HIP_MEMORY_SCOPE_AGENT);
    }
    __syncthreads();
  }
}

__global__ void loss_finalize(const float* __restrict__ lossp, int n, float* __restrict__ out) {
  __shared__ float red[256];
  float s = 0.f;
  for (int i = threadIdx.x; i < n; i += 256) s += lossp[i];
  red[threadIdx.x] = s;
  __syncthreads();
  for (int st = 128; st > 0; st >>= 1) {
    if (threadIdx.x < st) red[threadIdx.x] += red[threadIdx.x + st];
    __syncthreads();
  }
  if (threadIdx.x == 0) out[0] = red[0] * (1.0f / 71792640.0f);
}

// ---------------------------------------------------------------------------
extern "C" void kernel_launch(void* const* d_in, const int* in_sizes, int n_in,
                              void* d_out, int out_size, void* d_ws, size_t ws_size,
                              hipStream_t stream) {
  (void)in_sizes; (void)n_in; (void)out_size;
  const float* hs   = (const float*)d_in[0];
  const float* tmpl = (const float*)d_in[1];
  const float* vert = (const float*)d_in[2];
  const int*   tfm  = (const int*)  d_in[3];
  const float* wih0 = (const float*)d_in[4];
  const float* whh0 = (const float*)d_in[5];
  const float* bih0 = (const float*)d_in[6];
  const float* bhh0 = (const float*)d_in[7];
  const float* wih1 = (const float*)d_in[8];
  const float* whh1 = (const float*)d_in[9];
  const float* bih1 = (const float*)d_in[10];
  const float* bhh1 = (const float*)d_in[11];
  const float* fcw  = (const float*)d_in[12];
  const float* fcb  = (const float*)d_in[13];
  const float* redw = (const float*)d_in[14];
  const float* redb = (const float*)d_in[15];
  float* out = (float*)d_out;

  char* ws = (char*)d_ws;
  float*    LOSSP = (float*)(ws + 0);          // overlaps OUTG (dead by k3 time? NO —
  // OUTG is read by stage-2 inside k3; move LOSSP after M2 instead (see below)
  float*    OUTG  = (float*)(ws + 0);          // [768][1024]
  float*    OUTM  = (float*)(ws + 3145728);    // [768][256]
  float*    EXTRA = (float*)(ws + 3932160);    // [3][768]
  unsigned long long* H0P = (unsigned long long*)(ws + 3941376); // [2][512]
  unsigned long long* H1P = (unsigned long long*)(ws + 3949568); // [2][512]
  unsigned* PROG  = (unsigned*)(ws + 3957760); // producers[512] + S2C/S2T/S2P
  float*    GF    = (float*)(ws + 3960064);    // [1027][768]
  float*    MT    = (float*)(ws + 7115776);    // [256][768]
  float*    GIHS  = (float*)(ws + 7902208);    // [1024][768]
  float*    PM    = (float*)(ws + 11047936);   // [1027][768]
  float*    M2    = (float*)(ws + 14203648);   // [768][256]
  unsigned short* H1SB = (unsigned short*)(ws + 14990080); // [1024][256] bf16
  unsigned short* GF2B = (unsigned short*)(ws + 15514624); // [1024][768] bf16
  unsigned short* FB   = (unsigned short*)(ws + 17087488); // fcw bf16 [VD*256]
  LOSSP = (float*)(ws + 52983808);             // [4384] own region
  const size_t NEEDED = 52983808UL + 4384UL * 4UL;
  const int s2 = (ws_size >= NEEDED) ? 1 : 0;

  // zero split-K accumulators + EXTRA + tag buffers + progress (every call)
  hipMemsetAsync(d_ws, 0, 3960064, stream);

  if (s2) {
    tobf16<<<dim3(8764), 256, 0, stream>>>(fcw, FB, 17948160L);
    bigk_merged<<<dim3(3, 3, 21), 512, 0, stream>>>(redw, vert, fcw, OUTG, OUTM, 3344, 1);
  } else {
    bigk_merged<<<dim3(5, 3, 21), 512, 0, stream>>>(redw, vert, fcw, OUTG, OUTM, 3344, 0);
  }
  gemv3<<<dim3(96, 8), 256, 0, stream>>>(redw, tmpl, fcb, EXTRA);

  transpose_merged<<<dim3(32, 24, 2), 256, 0, stream>>>(OUTG, OUTM, EXTRA, redb, GF, MT, s2);
  gemm128x3<<<dim3(9, 6, 3), 256, 0, stream>>>(hs, wih0, GIHS, bih0, GF, PM, MT, M2, s2);

  // fused recurrence + fc GEMM + stage-2 (bigk n-blocks {1,3} -> GF2B -> PM)
  k3_fused<<<256, 512, 0, stream>>>(GIHS, PM, M2, whh0, bhh0, wih1, bih1, whh1, bhh1,
                                    tfm, H1SB, H0P, H1P, PROG,
                                    fcw, FB, s2, fcb, vert, out,
                                    s2 ? LOSSP : (float*)(ws + 0),
                                    redw, OUTG, GF2B, PM, redb, wih0 + 768);

  loss_finalize<<<1, 256, 0, stream>>>(s2 ? LOSSP : (float*)(ws + 0), 4384, out + 71792640L);
}

// Round 14
// 2402.455 us; speedup vs baseline: 1.3047x; 1.0410x over previous
//
#include <hip/hip_runtime.h>
#include <hip/hip_bf16.h>

// ---------------------------------------------------------------------------
// FaceXHuBERT decoder: 2-layer GRU (H=256) over T=512 + fc to V=70110 with
// teacher-forcing feedback through red_w [A=768, V].
//
// Round 14 (on top of r13's split-pipeline):
//   - gemv3 folded INTO bigk's OUTM blocks (each redw tile staged exactly
//     once there): EXTRA accumulated from the bf16 LDS A-tile. One less
//     launch + one less full redw read.
//   - stage-1 bigk z=21->28 (CHK=2528): 252 blocks, one occupancy round of
//     shorter blocks (-~50us).
//   - everything else identical to round 13 (passed, matched predictions).
// Structure: stage-1 prologue computes bigk n-blocks {0,2}+OUTM, transpose,
// PM row-blocks {0,1,4,5,8}; stage-2 (126 idle consumer WGs inside k3_fused)
// computes bigk n-blocks {1,3} -> GF2B(bf16) -> PM rows {2,3,6,7}; producers
// gate at t=256. Recurrence = round-10 schedule (measured best, ~1.9us/step
// latency floor).
// ---------------------------------------------------------------------------

#define TT 512
#define VD 70110
#define NR 1024

using bf16x8 = __attribute__((ext_vector_type(8))) short;
using f32x4  = __attribute__((ext_vector_type(4))) float;

static __device__ __forceinline__ unsigned short f2bf(float f) {
  unsigned u = __float_as_uint(f);
  u += 0x7FFFu + ((u >> 16) & 1u);   // RNE
  return (unsigned short)(u >> 16);
}
static __device__ __forceinline__ float bf2f(unsigned short b) {
  return __uint_as_float(((unsigned)b) << 16);
}

// ---------------- f32 -> bf16 conversion ------------------------------------
__global__ __launch_bounds__(256)
void tobf16(const float* __restrict__ src, unsigned short* __restrict__ dst, long n)
{
  const long c0 = ((long)blockIdx.x * 256 + threadIdx.x) * 8;
  if (c0 + 8 <= n) {
    const float2* s2 = (const float2*)(src + c0);
    unsigned short t[8] __attribute__((aligned(16)));
#pragma unroll
    for (int i = 0; i < 4; ++i) { float2 v = s2[i]; t[2*i] = f2bf(v.x); t[2*i+1] = f2bf(v.y); }
    *(int4*)(dst + c0) = *(int4*)t;
  } else {
    for (long c = c0; c < n; ++c) dst[c] = f2bf(src[c]);
  }
}

// ---------------- merged big split-K GEMM over V (bf16 MFMA, atomicAdd) -----
// xmap=1: blockIdx.x {0,1,2} -> x {0,2,4} (stage-1). xmap=0: identity (full).
// OUTM blocks (x==4) additionally accumulate EXTRA[v][a] (folded gemv3) from
// the bf16 A-tile: each (m,k) redw tile appears in exactly one OUTM block.
__global__ __launch_bounds__(512, 1)
void bigk_merged(const float* __restrict__ A, const float* __restrict__ vert,
                 const float* __restrict__ fcw,
                 const float* __restrict__ tmpl, const float* __restrict__ fcb,
                 float* __restrict__ extra,
                 float* __restrict__ OUTG, float* __restrict__ OUTM, int CHK, int xmap)
{
  __shared__ unsigned short Al[256][40];
  __shared__ unsigned short Bl[256][40];
  __shared__ float cS[3][32];
  const int tid = threadIdx.x;
  const int xs3[3] = {0, 2, 4};
  const int x = xmap ? xs3[blockIdx.x] : blockIdx.x;
  const bool bform = (x == 4);
  float* C      = bform ? OUTM : OUTG;
  const int ldc = bform ? 256 : 1024;
  const int N   = bform ? 256 : 1024;
  const int n0  = bform ? 0 : x * 256;
  const int m0  = blockIdx.y * 256;
  const int kc0 = blockIdx.z * CHK;
  const int kc1 = min(VD, kc0 + CHK);
  const int wave = tid >> 6, lane = tid & 63;
  const int wm = wave >> 1, wn = wave & 1;
  const int kq = lane >> 4, ln = lane & 15;
  f32x4 acc[4][8] = {};
  float gv[3] = {0.f, 0.f, 0.f};        // folded-gemv partials (bform only)
  const int grow = tid >> 1, gkh = (tid & 1) * 16;
  for (int kc = kc0; kc < kc1; kc += 32) {
    __syncthreads();
    {
      const int m = tid >> 1, kh = (tid & 1) << 4;
      const float* arow = A + (long)(m0 + m) * (long)VD;
      unsigned short tmp[16] __attribute__((aligned(16)));
      if (kc + 32 <= kc1) {
        const float2* ap2 = (const float2*)(arow + kc + kh);
#pragma unroll
        for (int i = 0; i < 8; ++i) { float2 v = ap2[i]; tmp[2*i] = f2bf(v.x); tmp[2*i+1] = f2bf(v.y); }
      } else {
#pragma unroll
        for (int i = 0; i < 16; ++i) {
          int kk = kc + kh + i;
          tmp[i] = f2bf((kk < kc1) ? arow[kk] : 0.f);
        }
      }
      ((int4*)&Al[m][kh])[0] = *(int4*)&tmp[0];
      ((int4*)&Al[m][kh])[1] = *(int4*)&tmp[8];
    }
    if (!bform) {
      const int n = tid >> 1, kh = (tid & 1) << 4;
      const float* bp = vert + (long)(n0 + n) * (long)VD;
      unsigned short tmp[16] __attribute__((aligned(16)));
      if (kc + 32 <= kc1) {
        const float2* bp2 = (const float2*)(bp + kc + kh);
#pragma unroll
        for (int i = 0; i < 8; ++i) { float2 v = bp2[i]; tmp[2*i] = f2bf(v.x); tmp[2*i+1] = f2bf(v.y); }
      } else {
#pragma unroll
        for (int i = 0; i < 16; ++i) {
          int kk = kc + kh + i;
          tmp[i] = f2bf((kk < kc1) ? bp[kk] : 0.f);
        }
      }
      ((int4*)&Bl[n][kh])[0] = *(int4*)&tmp[0];
      ((int4*)&Bl[n][kh])[1] = *(int4*)&tmp[8];
    } else {
      const int n = tid & 255, kh = (tid >> 8) << 4;
      unsigned short tmp[16] __attribute__((aligned(16)));
#pragma unroll
      for (int i = 0; i < 16; ++i) {
        int kk = kc + kh + i;
        float v = 0.f;
        if (kk < kc1 && n < 256) v = fcw[(long)kk * 256 + n];
        tmp[i] = f2bf(v);
      }
      ((int4*)&Bl[n][kh])[0] = *(int4*)&tmp[0];
      ((int4*)&Bl[n][kh])[1] = *(int4*)&tmp[8];
      // stage gemv c-vectors for this k-slice
      if (tid < 96) {
        const int v = tid >> 5, i = tid & 31;
        const int kk = kc + i;
        float cv = 0.f;
        if (kk < kc1) {
          if (v == 0) cv = tmpl[kk];
          else if (v == 1) cv = tmpl[(long)VD + kk];
          else cv = fcb[kk];
        }
        cS[v][i] = cv;
      }
    }
    __syncthreads();
    if (bform) {   // folded gemv: rows split across thread pairs (16 k each)
#pragma unroll
      for (int i = 0; i < 16; ++i) {
        const float a = bf2f(Al[grow][gkh + i]);
        gv[0] += a * cS[0][gkh + i];
        gv[1] += a * cS[1][gkh + i];
        gv[2] += a * cS[2][gkh + i];
      }
    }
    bf16x8 af[4], bfv[8];
#pragma unroll
    for (int i = 0; i < 4; ++i) af[i] = *(const bf16x8*)&Al[wm*64 + i*16 + ln][kq*8];
#pragma unroll
    for (int j = 0; j < 8; ++j) bfv[j] = *(const bf16x8*)&Bl[wn*128 + j*16 + ln][kq*8];
#pragma unroll
    for (int i = 0; i < 4; ++i)
#pragma unroll
      for (int j = 0; j < 8; ++j)
        acc[i][j] = __builtin_amdgcn_mfma_f32_16x16x32_bf16(af[i], bfv[j], acc[i][j], 0, 0, 0);
  }
  if (bform) {
#pragma unroll
    for (int v = 0; v < 3; ++v) {
      gv[v] += __shfl_xor(gv[v], 1);
      if ((tid & 1) == 0) unsafeAtomicAdd(&extra[v * 768 + m0 + grow], gv[v]);
    }
  }
#pragma unroll
  for (int i = 0; i < 4; ++i)
#pragma unroll
    for (int j = 0; j < 8; ++j)
#pragma unroll
      for (int r = 0; r < 4; ++r) {
        int gm = m0 + wm*64 + i*16 + kq*4 + r;
        int gn = n0 + wn*128 + j*16 + ln;
        if (gn < N) unsafeAtomicAdd(&C[(long)gm * ldc + gn], acc[i][j][r]);
      }
}

// ---------------- merged transposes (+red_b) + fixup ------------------------
static __device__ __forceinline__ void transpose_body(
    const float* src, int lds, float* dst, int ldd,
    int rows, int cols, const float* bias, int bx, int by)
{
  __shared__ float tile[32][33];
  const int rb = bx * 32, cb = by * 32;
  const int tx = threadIdx.x & 31, ty = threadIdx.x >> 5;
  for (int yy = ty; yy < 32; yy += 8) {
    int c = cb + yy, r = rb + tx;
    tile[yy][tx] = (c < cols && r < rows) ? src[(long)c * lds + r] : 0.f;
  }
  __syncthreads();
  for (int yy = ty; yy < 32; yy += 8) {
    int r = rb + yy, c = cb + tx;
    if (r < rows && c < cols)
      dst[(long)r * ldd + c] = tile[tx][yy] + (bias ? bias[c] : 0.f);
  }
}

__global__ void transpose_merged(const float* __restrict__ OUTG,
                                 const float* __restrict__ OUTM,
                                 const float* __restrict__ extra,
                                 const float* __restrict__ redb,
                                 float* __restrict__ GF, float* __restrict__ MT,
                                 int s2on)
{
  if (blockIdx.z == 0) {
    int bx = blockIdx.x;
    if (s2on) {                 // stage-1 only rows 0-255 and 512-767
      if (bx >= 16) return;
      bx = (bx < 8) ? bx : bx + 8;
    }
    transpose_body(OUTG, 1024, GF, 768, 1024, 768, redb, bx, blockIdx.y);
  } else {
    if (blockIdx.x < 8) {
      transpose_body(OUTM, 256, MT, 768, 256, 768, nullptr, blockIdx.x, blockIdx.y);
    } else if (blockIdx.x == 8 && blockIdx.y == 0) {
      for (int i = threadIdx.x; i < 3 * 768; i += 256) {
        const int b = i / 768, a = i - b * 768;
        GF[(long)(1024 + b) * 768 + a] = extra[i] + redb[a];
      }
    }
  }
}

// ---------------- merged small GEMMs (gihs / PM-stage1 / M2) ----------------
__global__ __launch_bounds__(256, 2)
void gemm128x3(const float* __restrict__ hs, const float* __restrict__ wih0,
               float* __restrict__ GIHS, const float* __restrict__ bih0,
               const float* __restrict__ GF, float* __restrict__ PM,
               const float* __restrict__ MT, float* __restrict__ M2, int s2on)
{
  const float *A, *B, *bias = nullptr; float* C;
  int lda, ldb, M, N, K; long ldc; int mblk = blockIdx.x;
  if (blockIdx.z == 0) {
    if (blockIdx.x >= 8) return;
    A = hs; lda = 768; B = wih0; ldb = 1536; C = GIHS; ldc = 768; bias = bih0;
    M = 1024; N = 768; K = 768;
  } else if (blockIdx.z == 1) {
    if (s2on) {               // stage-1 PM row blocks {0,1,4,5,8}
      const int tbl[5] = {0, 1, 4, 5, 8};
      if (blockIdx.x >= 5) return;
      mblk = tbl[blockIdx.x];
    }
    A = GF; lda = 768; B = wih0 + 768; ldb = 1536; C = PM; ldc = 768;
    M = 1027; N = 768; K = 768;
  } else {
    if (blockIdx.x >= 6 || blockIdx.y >= 2) return;
    A = wih0 + 768; lda = 1536; B = MT; ldb = 768; C = M2; ldc = 256;
    M = 768; N = 256; K = 768;
  }
  __shared__ unsigned short Al[128][40];
  __shared__ unsigned short Bl[128][40];
  const int tid = threadIdx.x;
  const int m0 = mblk * 128, n0 = blockIdx.y * 128;
  const int wave = tid >> 6, lane = tid & 63;
  const int wm = wave >> 1, wn = wave & 1;
  const int kq = lane >> 4, ln = lane & 15;
  f32x4 acc[4][4] = {};
  for (int kc = 0; kc < K; kc += 32) {
    __syncthreads();
    {
      const int m = tid >> 1, kh = (tid & 1) << 4;
      unsigned short tmp[16] __attribute__((aligned(16)));
      const bool mok = (m0 + m) < M;
      if (mok) {
        const float4* ap4 = (const float4*)(A + (long)(m0 + m) * lda + kc + kh);
#pragma unroll
        for (int i = 0; i < 4; ++i) {
          float4 v = ap4[i];
          tmp[4*i+0] = f2bf(v.x); tmp[4*i+1] = f2bf(v.y);
          tmp[4*i+2] = f2bf(v.z); tmp[4*i+3] = f2bf(v.w);
        }
      } else {
#pragma unroll
        for (int i = 0; i < 16; ++i) tmp[i] = 0;
      }
      ((int4*)&Al[m][kh])[0] = *(int4*)&tmp[0];
      ((int4*)&Al[m][kh])[1] = *(int4*)&tmp[8];
      const int n = m;
      unsigned short tmb[16] __attribute__((aligned(16)));
      const bool nok = (n0 + n) < N;
      if (nok) {
        const float4* bp4 = (const float4*)(B + (long)(n0 + n) * ldb + kc + kh);
#pragma unroll
        for (int i = 0; i < 4; ++i) {
          float4 v = bp4[i];
          tmb[4*i+0] = f2bf(v.x); tmb[4*i+1] = f2bf(v.y);
          tmb[4*i+2] = f2bf(v.z); tmb[4*i+3] = f2bf(v.w);
        }
      } else {
#pragma unroll
        for (int i = 0; i < 16; ++i) tmb[i] = 0;
      }
      ((int4*)&Bl[n][kh])[0] = *(int4*)&tmb[0];
      ((int4*)&Bl[n][kh])[1] = *(int4*)&tmb[8];
    }
    __syncthreads();
    bf16x8 af[4], bfv[4];
#pragma unroll
    for (int i = 0; i < 4; ++i) af[i]  = *(const bf16x8*)&Al[wm*64 + i*16 + ln][kq*8];
#pragma unroll
    for (int j = 0; j < 4; ++j) bfv[j] = *(const bf16x8*)&Bl[wn*64 + j*16 + ln][kq*8];
#pragma unroll
    for (int i = 0; i < 4; ++i)
#pragma unroll
      for (int j = 0; j < 4; ++j)
        acc[i][j] = __builtin_amdgcn_mfma_f32_16x16x32_bf16(af[i], bfv[j], acc[i][j], 0, 0, 0);
  }
#pragma unroll
  for (int i = 0; i < 4; ++i)
#pragma unroll
    for (int j = 0; j < 4; ++j)
#pragma unroll
      for (int r = 0; r < 4; ++r) {
        const int gm = m0 + wm*64 + i*16 + kq*4 + r;
        const int gn = n0 + wn*64 + j*16 + ln;
        if (gm < M && gn < N) {
          float v = acc[i][j][r];
          if (bias) v += bias[gn];
          C[(long)gm * ldc + gn] = v;
        }
      }
}

// ---------------- fused recurrence + fc GEMM + stage-2 ----------------------
struct ProdLds {
  float wq[24][260], wh0s[24][260], wi1s[24][260], wh1s[24][260];
  float h0c[2][256], h1c[2][256];
  float dotsS[2][2][3][8];
  int tfl[TT];
};
struct ConsLds {
  unsigned short As[128][264];
  unsigned short Bl[128][40];
  float wred[8];
};
struct S2Lds {
  unsigned short Al[256][40];
  unsigned short Bl[256][40];
};

#define HALF_DOTS(W, H, MS)                                                   \
  {                                                                           \
    const int g8_ = tid >> 3, l8_ = tid & 7;                                  \
    if (g8_ < 48) {                                                           \
      const int row_ = g8_ >> 1, bb_ = g8_ & 1;                               \
      const float4* w4_ = (const float4*)&(W)[row_][0];                       \
      const float4* h4_ = (const float4*)&(H)[bb_][0];                        \
      float s_ = 0.f;                                                         \
      _Pragma("unroll")                                                       \
      for (int i = 0; i < 8; ++i) {                                           \
        const float4 a_ = w4_[i * 8 + l8_], h_ = h4_[i * 8 + l8_];            \
        s_ += a_.x * h_.x + a_.y * h_.y + a_.z * h_.z + a_.w * h_.w;          \
      }                                                                       \
      s_ += __shfl_xor(s_, 1); s_ += __shfl_xor(s_, 2); s_ += __shfl_xor(s_, 4); \
      if (l8_ == 0) dotsS[MS][bb_][row_ >> 3][row_ & 7] = s_;                 \
    }                                                                         \
  }

#define POLL_ISSUE(buf, var)                                                  \
  unsigned long long var = __hip_atomic_load(&(buf)[tid], __ATOMIC_RELAXED, __HIP_MEMORY_SCOPE_AGENT);
#define POLL_FINISH(buf, var, dstLds, want)                                   \
  {                                                                           \
    const unsigned w_ = (unsigned)(want); int sp_ = 0;                        \
    while ((unsigned)(var >> 32) < w_ && ++sp_ < (1 << 15)) {                 \
      __builtin_amdgcn_s_sleep(1);                                            \
      var = __hip_atomic_load(&(buf)[tid], __ATOMIC_RELAXED, __HIP_MEMORY_SCOPE_AGENT); \
    }                                                                         \
    ((float*)dstLds)[tid] = __uint_as_float((unsigned)var);                   \
  }
#define POLLP(buf, dstLds, want)                                              \
  { POLL_ISSUE(buf, pw_); POLL_FINISH(buf, pw_, dstLds, want); }

__global__ __launch_bounds__(512, 1)
void k3_fused(const float* __restrict__ gihs, const float* Pm,
              const float* __restrict__ M2m,
              const float* __restrict__ whh0, const float* __restrict__ bhh0,
              const float* __restrict__ wih1, const float* __restrict__ bih1,
              const float* __restrict__ whh1, const float* __restrict__ bhh1,
              const int* __restrict__ tfm,
              unsigned short* __restrict__ h1sb,
              unsigned long long* __restrict__ h0p, unsigned long long* __restrict__ h1p,
              unsigned* __restrict__ prog,
              const float* __restrict__ fcw, const unsigned short* __restrict__ FB,
              int s2on,
              const float* __restrict__ fcb, const float* __restrict__ vert,
              float* __restrict__ out, float* __restrict__ lossp,
              const float* __restrict__ redw, float* __restrict__ outg,
              unsigned short* __restrict__ gf2b, float* pmw,
              const float* __restrict__ redb, const float* __restrict__ wr)
{
  __shared__ union { ProdLds p; ConsLds c; S2Lds s; } U;
  const int tid = threadIdx.x;

  if (blockIdx.x >= 32) {
    const int idx = blockIdx.x - 32;

    // ================= STAGE 2 (126 of the tx=3 WGs) =======================
    if (s2on && idx >= 96 && idx < 222) {
      const int r2 = idx - 96;           // 0..125
      { // ---- one bigk block for n-blocks {1,3} (f32 staging path) ---------
        auto& S = U.s;
        const int x2 = (r2 < 63) ? 1 : 3;
        const int rem = (r2 < 63) ? r2 : r2 - 63;
        const int m0 = (rem / 21) * 256;
        const int kc0 = (rem % 21) * 3344;
        const int kc1 = min(VD, kc0 + 3344);
        const int n0 = x2 * 256;
        const int wave = tid >> 6, lane = tid & 63;
        const int wm = wave >> 1, wn = wave & 1;
        const int kq = lane >> 4, ln = lane & 15;
        f32x4 acc[4][8] = {};
        for (int kc = kc0; kc < kc1; kc += 32) {
          __syncthreads();
          {
            const int m = tid >> 1, kh = (tid & 1) << 4;
            const float* arow = redw + (long)(m0 + m) * (long)VD;
            unsigned short tmp[16] __attribute__((aligned(16)));
            if (kc + 32 <= kc1) {
              const float2* ap2 = (const float2*)(arow + kc + kh);
#pragma unroll
              for (int i = 0; i < 8; ++i) { float2 v = ap2[i]; tmp[2*i] = f2bf(v.x); tmp[2*i+1] = f2bf(v.y); }
            } else {
#pragma unroll
              for (int i = 0; i < 16; ++i) {
                int kk = kc + kh + i;
                tmp[i] = f2bf((kk < kc1) ? arow[kk] : 0.f);
              }
            }
            ((int4*)&S.Al[m][kh])[0] = *(int4*)&tmp[0];
            ((int4*)&S.Al[m][kh])[1] = *(int4*)&tmp[8];
            const float* bp = vert + (long)(n0 + m) * (long)VD;
            unsigned short tmb[16] __attribute__((aligned(16)));
            if (kc + 32 <= kc1) {
              const float2* bp2 = (const float2*)(bp + kc + kh);
#pragma unroll
              for (int i = 0; i < 8; ++i) { float2 v = bp2[i]; tmb[2*i] = f2bf(v.x); tmb[2*i+1] = f2bf(v.y); }
            } else {
#pragma unroll
              for (int i = 0; i < 16; ++i) {
                int kk = kc + kh + i;
                tmb[i] = f2bf((kk < kc1) ? bp[kk] : 0.f);
              }
            }
            ((int4*)&S.Bl[m][kh])[0] = *(int4*)&tmb[0];
            ((int4*)&S.Bl[m][kh])[1] = *(int4*)&tmb[8];
          }
          __syncthreads();
          bf16x8 af[4], bfv[8];
#pragma unroll
          for (int i = 0; i < 4; ++i) af[i] = *(const bf16x8*)&S.Al[wm*64 + i*16 + ln][kq*8];
#pragma unroll
          for (int j = 0; j < 8; ++j) bfv[j] = *(const bf16x8*)&S.Bl[wn*128 + j*16 + ln][kq*8];
#pragma unroll
          for (int i = 0; i < 4; ++i)
#pragma unroll
            for (int j = 0; j < 8; ++j)
              acc[i][j] = __builtin_amdgcn_mfma_f32_16x16x32_bf16(af[i], bfv[j], acc[i][j], 0, 0, 0);
        }
#pragma unroll
        for (int i = 0; i < 4; ++i)
#pragma unroll
          for (int j = 0; j < 8; ++j)
#pragma unroll
            for (int r = 0; r < 4; ++r) {
              const int gm = m0 + wm*64 + i*16 + kq*4 + r;
              const int gn = n0 + wn*128 + j*16 + ln;
              unsafeAtomicAdd(&outg[(long)gm * 1024 + gn], acc[i][j][r]);
            }
        __syncthreads();
        if (tid == 0)
          (void)__hip_atomic_fetch_add(&prog[512], 1u, __ATOMIC_RELAXED, __HIP_MEMORY_SCOPE_AGENT);
      }
      if (r2 < 24) {
        // ---- wait all 126 bigk blocks, then transpose OUTG->GF2B (bf16) ----
        if (tid == 0) {
          int sp = 0;
          while (__hip_atomic_load(&prog[512], __ATOMIC_RELAXED, __HIP_MEMORY_SCOPE_AGENT) < 126u) {
            if (++sp > (1 << 16)) break;
            for (int j = 0; j < 8; ++j) __builtin_amdgcn_s_sleep(15);
          }
        }
        __syncthreads();
        const int yy = tid >> 4, pr = tid & 15;
        for (int i = 0; i < 16; ++i) {
          const int tt = r2 * 16 + i;               // 0..383
          const int bxI = tt / 24, by = tt % 24;
          const int bx = (bxI < 8) ? (8 + bxI) : (16 + bxI);   // rows 256-511, 768-1023
          const int r = bx * 32 + yy;
          const int c = by * 32 + pr * 2;
          float f0 = __hip_atomic_load(&outg[(long)c * 1024 + r],
                                       __ATOMIC_RELAXED, __HIP_MEMORY_SCOPE_AGENT);
          float f1 = __hip_atomic_load(&outg[(long)(c + 1) * 1024 + r],
                                       __ATOMIC_RELAXED, __HIP_MEMORY_SCOPE_AGENT);
          const unsigned pk = (unsigned)f2bf(f0 + redb[c]) |
                              ((unsigned)f2bf(f1 + redb[c + 1]) << 16);
          __hip_atomic_store((unsigned*)gf2b + ((long)r * 384 + (c >> 1)), pk,
                             __ATOMIC_RELAXED, __HIP_MEMORY_SCOPE_AGENT);
        }
        if (tid == 0)
          (void)__hip_atomic_fetch_add(&prog[520], 1u, __ATOMIC_RELAXED, __HIP_MEMORY_SCOPE_AGENT);
        if (tid == 0) {
          int sp = 0;
          while (__hip_atomic_load(&prog[520], __ATOMIC_RELAXED, __HIP_MEMORY_SCOPE_AGENT) < 24u) {
            if (++sp > (1 << 16)) break;
            for (int j = 0; j < 4; ++j) __builtin_amdgcn_s_sleep(15);
          }
        }
        __syncthreads();
        // ---- one 128x128 PM tile (row blocks {2,3,6,7} x 6 col blocks) ----
        {
          auto& S = U.s;
          unsigned short (*Als)[40] = (unsigned short(*)[40])&S.Al[0][0];
          unsigned short (*Bls)[40] = (unsigned short(*)[40])&S.Bl[0][0];
          const int rowtbl[4] = {2, 3, 6, 7};
          const int m0 = rowtbl[r2 / 6] * 128;
          const int n0 = (r2 % 6) * 128;
          const int wave = tid >> 6, lane = tid & 63;
          const int wm = wave >> 2, wn = wave & 3;
          const int kq = lane >> 4, ln = lane & 15;
          f32x4 acc[4][2] = {};
          for (int kc = 0; kc < 768; kc += 32) {
            __syncthreads();
            {
              const unsigned* g2 = (const unsigned*)gf2b;
#pragma unroll
              for (int i = 0; i < 4; ++i) {
                const int u = tid * 4 + i;          // 0..2047
                const int row = u >> 4, cp = u & 15;
                unsigned v = __hip_atomic_load(&g2[(long)(m0 + row) * 384 + (kc >> 1) + cp],
                                               __ATOMIC_RELAXED, __HIP_MEMORY_SCOPE_AGENT);
                *(unsigned*)&Als[row][cp * 2] = v;
              }
#pragma unroll
              for (int i = 0; i < 4; ++i) {
                const int u = tid * 4 + i;
                const int row = u >> 4, k2 = (u & 15) * 2;
                const float2 v = *(const float2*)&wr[(long)(n0 + row) * 1536 + kc + k2];
                const unsigned pk = (unsigned)f2bf(v.x) | ((unsigned)f2bf(v.y) << 16);
                *(unsigned*)&Bls[row][k2] = pk;
              }
            }
            __syncthreads();
            bf16x8 af[4], bfv[2];
#pragma unroll
            for (int i = 0; i < 4; ++i)
              af[i] = *(const bf16x8*)&Als[wm*64 + i*16 + ln][kq*8];
#pragma unroll
            for (int j = 0; j < 2; ++j)
              bfv[j] = *(const bf16x8*)&Bls[wn*32 + j*16 + ln][kq*8];
#pragma unroll
            for (int i = 0; i < 4; ++i)
#pragma unroll
              for (int j = 0; j < 2; ++j)
                acc[i][j] = __builtin_amdgcn_mfma_f32_16x16x32_bf16(af[i], bfv[j], acc[i][j], 0, 0, 0);
          }
#pragma unroll
          for (int i = 0; i < 4; ++i)
#pragma unroll
            for (int j = 0; j < 2; ++j)
#pragma unroll
              for (int r = 0; r < 4; ++r) {
                const int gm = m0 + wm*64 + i*16 + kq*4 + r;
                const int gn = n0 + wn*32 + j*16 + ln;
                __hip_atomic_store(&pmw[(long)gm * 768 + gn], acc[i][j][r],
                                   __ATOMIC_RELAXED, __HIP_MEMORY_SCOPE_AGENT);
              }
        }
        __syncthreads();
        if (tid == 0)
          (void)__hip_atomic_fetch_add(&prog[528], 1u, __ATOMIC_RELAXED, __HIP_MEMORY_SCOPE_AGENT);
      }
      __syncthreads();
    }

    // ================= CONSUMER: fc GEMM tile sweep ========================
    auto& C = U.c;
    int tx, memb, cnt;
    if (idx < 24)      { tx = 0; memb = (idx)      >> 1; cnt = 12; }
    else if (idx < 48) { tx = 1; memb = (idx - 24) >> 1; cnt = 12; }
    else if (idx < 96) { tx = 2; memb = (idx - 48) >> 1; cnt = 24; }
    else               { tx = 3; memb = (idx - 96) >> 1; cnt = 64; }
    const int b = idx & 1;
    const int nt0 = memb * 548 / cnt, nt1 = (memb + 1) * 548 / cnt;
    if (nt0 >= nt1) return;
    const unsigned want = (unsigned)((tx + 1) * 128);
    if (tid < 32) {
      int sp = 0;
      while (__hip_atomic_load(&prog[tid * 16], __ATOMIC_RELAXED, __HIP_MEMORY_SCOPE_AGENT) < want) {
        if (++sp > (1 << 14)) break;
        for (int j = 0; j < 16; ++j) __builtin_amdgcn_s_sleep(15);
      }
    }
    __syncthreads();
    const long rbase = (long)b * 512 + (long)tx * 128;
    {
      const unsigned long long* src = (const unsigned long long*)(h1sb + rbase * 256);
#pragma unroll
      for (int i = 0; i < 16; ++i) {
        const int u = tid * 16 + i;
        unsigned long long v = __hip_atomic_load(&src[u], __ATOMIC_RELAXED, __HIP_MEMORY_SCOPE_AGENT);
        const int row = u >> 6, c4 = u & 63;
        *(unsigned long long*)&C.As[row][c4 * 4] = v;
      }
    }
    __syncthreads();
    const int wave = tid >> 6, lane = tid & 63;
    const int wm = wave >> 2, wn = wave & 3;
    const int kq = lane >> 4, ln = lane & 15;
    for (int nt = nt0; nt < nt1; ++nt) {
      const int n0 = nt * 128;
      f32x4 acc[4][2] = {};
#pragma unroll 1
      for (int ks = 0; ks < 8; ++ks) {
        __syncthreads();
        {
          const int rn = tid >> 2, kh = (tid & 3) * 8;
          const int gn = n0 + rn;
          if (s2on) {
            int4 v = {0, 0, 0, 0};
            if (gn < VD) v = *(const int4*)(FB + (long)gn * 256 + ks * 32 + kh);
            *(int4*)&C.Bl[rn][kh] = v;
          } else {
            unsigned short tmb[8] __attribute__((aligned(16)));
            if (gn < VD) {
              const float4* bp = (const float4*)&fcw[(long)gn * 256 + ks * 32 + kh];
              float4 v0 = bp[0], v1 = bp[1];
              tmb[0] = f2bf(v0.x); tmb[1] = f2bf(v0.y); tmb[2] = f2bf(v0.z); tmb[3] = f2bf(v0.w);
              tmb[4] = f2bf(v1.x); tmb[5] = f2bf(v1.y); tmb[6] = f2bf(v1.z); tmb[7] = f2bf(v1.w);
            } else {
#pragma unroll
              for (int i = 0; i < 8; ++i) tmb[i] = 0;
            }
            *(int4*)&C.Bl[rn][kh] = *(int4*)tmb;
          }
        }
        __syncthreads();
        bf16x8 af[4], bfv[2];
#pragma unroll
        for (int i = 0; i < 4; ++i)
          af[i] = *(const bf16x8*)&C.As[wm*64 + i*16 + ln][ks*32 + kq*8];
#pragma unroll
        for (int j = 0; j < 2; ++j)
          bfv[j] = *(const bf16x8*)&C.Bl[wn*32 + j*16 + ln][kq*8];
#pragma unroll
        for (int i = 0; i < 4; ++i)
#pragma unroll
          for (int j = 0; j < 2; ++j)
            acc[i][j] = __builtin_amdgcn_mfma_f32_16x16x32_bf16(af[i], bfv[j], acc[i][j], 0, 0, 0);
      }
      float ls = 0.f;
#pragma unroll
      for (int i = 0; i < 4; ++i)
#pragma unroll
        for (int j = 0; j < 2; ++j)
#pragma unroll
          for (int r = 0; r < 4; ++r) {
            const int gmL = wm*64 + i*16 + kq*4 + r;
            const int gn = n0 + wn*32 + j*16 + ln;
            if (gn < VD) {
              const float v = acc[i][j][r] + fcb[gn];
              const long grow = rbase + gmL;
              out[grow * VD + gn] = v;
              const float dd = v - vert[grow * VD + gn];
              ls += dd * dd;
            }
          }
#pragma unroll
      for (int o = 32; o > 0; o >>= 1) ls += __shfl_down(ls, o);
      if (lane == 0) C.wred[wave] = ls;
      __syncthreads();
      if (tid == 0) {
        float s = 0.f;
#pragma unroll
        for (int w = 0; w < 8; ++w) s += C.wred[w];
        lossp[(tx * 2 + b) * 548 + nt] = s;
      }
      __syncthreads();
    }
    return;
  }

  // ================= PRODUCER: round-10 schedule + stage-2 gate ============
  float (&wq)[24][260]   = U.p.wq;
  float (&wh0s)[24][260] = U.p.wh0s;
  float (&wi1s)[24][260] = U.p.wi1s;
  float (&wh1s)[24][260] = U.p.wh1s;
  float (&h0c)[2][256]   = U.p.h0c;
  float (&h1c)[2][256]   = U.p.h1c;
  float (&dotsS)[2][2][3][8] = U.p.dotsS;
  int   (&tfl)[TT]       = U.p.tfl;
  const int wg = blockIdx.x;
  const int j0 = wg * 8;

  {
    const int col = tid & 255, rh = tid >> 8;
    for (int row = rh; row < 24; row += 2) {
      const int g = row >> 3, jj = row & 7;
      const long gr = g * 256 + j0 + jj;
      wq[row][col]   = M2m[gr * 256 + col];
      wh0s[row][col] = whh0[gr * 256 + col];
      wi1s[row][col] = wih1[gr * 256 + col];
      wh1s[row][col] = whh1[gr * 256 + col];
    }
  }
  ((float*)h0c)[tid] = 0.f;
  ((float*)h1c)[tid] = 0.f;
  if (tid < TT) tfl[tid] = tfm[tid];

  const int cb = tid >> 3, cjj = tid & 7, cj = j0 + cjj;
  float bh0v[3], bi1v[3], bh1v[3], d2v[3];
  if (tid < 16) {
#pragma unroll
    for (int g = 0; g < 3; ++g) {
      bh0v[g] = bhh0[g*256 + cj];
      bi1v[g] = bih1[g*256 + cj];
      bh1v[g] = bhh1[g*256 + cj];
      d2v[g]  = Pm[(long)1026 * 768 + g*256 + cj];
    }
  }
  __syncthreads();

  const int wave = tid >> 6;
  float gihsv[3], piv[3];
  if (tid < 16) {
#pragma unroll
    for (int g = 0; g < 3; ++g) {
      gihsv[g] = gihs[((long)cb * TT) * 768 + g*256 + cj];
      piv[g]   = Pm[(long)(1024 + cb) * 768 + g*256 + cj];
    }
  }
  for (int t = 0; t < TT; ++t) {
    if (s2on && t == 256) {     // PM rows >=256 become readable only now
      if (tid == 0) {
        int sp = 0;
        while (__hip_atomic_load(&prog[528], __ATOMIC_RELAXED, __HIP_MEMORY_SCOPE_AGENT) < 24u) {
          if (++sp > (1 << 18)) break;
          __builtin_amdgcn_s_sleep(8);
        }
      }
      __syncthreads();
    }
    const int tfprev = (t == 0) ? 1 : tfl[t - 1];
    // ---- phase A
    if (!tfprev) {
      POLL_ISSUE(h1p + (t & 1) * 512, pb);
      HALF_DOTS(wh0s, h0c, 1);
      POLL_FINISH(h1p + (t & 1) * 512, pb, h1c, t);
      __syncthreads();
      HALF_DOTS(wq, h1c, 0);
    } else {
      HALF_DOTS(wh0s, h0c, 1);
    }
    __syncthreads();
    if (tid < 16) {
      float gi[3], gh[3];
#pragma unroll
      for (int g = 0; g < 3; ++g) {
        const float q = tfprev ? 0.f : (dotsS[0][cb][g][cjj] + d2v[g]);
        gi[g] = gihsv[g] + (tfprev ? piv[g] : q);
        gh[g] = dotsS[1][cb][g][cjj] + bh0v[g];
      }
      const float rr = 1.f / (1.f + __expf(-(gi[0] + gh[0])));
      const float zz = 1.f / (1.f + __expf(-(gi[1] + gh[1])));
      const float nn = tanhf(gi[2] + rr * gh[2]);
      const float h0n = (1.f - zz) * nn + zz * h0c[cb][cj];
      const unsigned long long pk =
          ((unsigned long long)(unsigned)(t + 1) << 32) | (unsigned long long)__float_as_uint(h0n);
      __hip_atomic_store(&h0p[((t + 1) & 1) * 512 + cb * 256 + cj], pk,
                         __ATOMIC_RELAXED, __HIP_MEMORY_SCOPE_AGENT);
    }
    if (tid < 16 && t + 1 < TT) {
#pragma unroll
      for (int g = 0; g < 3; ++g) {
        gihsv[g] = gihs[((long)cb * TT + (t + 1)) * 768 + g*256 + cj];
        piv[g]   = Pm[((long)cb * TT + t) * 768 + g*256 + cj];
      }
    }
    __syncthreads();
    // ---- phase B: h0 exchange hidden under the independent wh1s half
    POLL_ISSUE(h0p + ((t + 1) & 1) * 512, hw);
    if (tfprev) {
      POLL_ISSUE(h1p + (t & 1) * 512, qb);
      POLL_FINISH(h1p + (t & 1) * 512, qb, h1c, t);
      __syncthreads();
    }
    HALF_DOTS(wh1s, h1c, 1);
    POLL_FINISH(h0p + ((t + 1) & 1) * 512, hw, h0c, t + 1);
    __syncthreads();
    HALF_DOTS(wi1s, h0c, 0);
    __syncthreads();
    if (tid < 16) {
      float gi[3], gh[3];
#pragma unroll
      for (int g = 0; g < 3; ++g) {
        gi[g] = dotsS[0][cb][g][cjj] + bi1v[g];
        gh[g] = dotsS[1][cb][g][cjj] + bh1v[g];
      }
      const float rr = 1.f / (1.f + __expf(-(gi[0] + gh[0])));
      const float zz = 1.f / (1.f + __expf(-(gi[1] + gh[1])));
      const float nn = tanhf(gi[2] + rr * gh[2]);
      const float h1n = (1.f - zz) * nn + zz * h1c[cb][cj];
      const unsigned hb = (unsigned)f2bf(h1n);
      asm volatile("global_store_short %0, %1, off sc0 sc1"
                   :: "v"(&h1sb[((long)cb * TT + t) * 256 + cj]), "v"(hb) : "memory");
      const unsigned long long pk =
          ((unsigned long long)(unsigned)(t + 1) << 32) | (unsigned long long)__float_as_uint(h1n);
      __hip_atomic_store(&h1p[((t + 1) & 1) * 512 + cb * 256 + cj], pk,
                         __ATOMIC_RELAXED, __HIP_MEMORY_SCOPE_AGENT);
    }
    if ((t & 15) == 15) {
      if (wave == 0) asm volatile("s_waitcnt vmcnt(0)" ::: "memory");
      if (tid == 0)
        __hip_atomic_store(&prog[wg * 16], (unsigned)(t + 1),
                           __ATOMIC_RELAXED, __HIP_MEMORY_SCOPE_AGENT);
    }
    __syncthreads();
  }
}

__global__ void loss_finalize(const float* __restrict__ lossp, int n, float* __restrict__ out) {
  __shared__ float red[256];
  float s = 0.f;
  for (int i = threadIdx.x; i < n; i += 256) s += lossp[i];
  red[threadIdx.x] = s;
  __syncthreads();
  for (int st = 128; st > 0; st >>= 1) {
    if (threadIdx.x < st) red[threadIdx.x] += red[threadIdx.x + st];
    __syncthreads();
  }
  if (threadIdx.x == 0) out[0] = red[0] * (1.0f / 71792640.0f);
}

// ---------------------------------------------------------------------------
extern "C" void kernel_launch(void* const* d_in, const int* in_sizes, int n_in,
                              void* d_out, int out_size, void* d_ws, size_t ws_size,
                              hipStream_t stream) {
  (void)in_sizes; (void)n_in; (void)out_size;
  const float* hs   = (const float*)d_in[0];
  const float* tmpl = (const float*)d_in[1];
  const float* vert = (const float*)d_in[2];
  const int*   tfm  = (const int*)  d_in[3];
  const float* wih0 = (const float*)d_in[4];
  const float* whh0 = (const float*)d_in[5];
  const float* bih0 = (const float*)d_in[6];
  const float* bhh0 = (const float*)d_in[7];
  const float* wih1 = (const float*)d_in[8];
  const float* whh1 = (const float*)d_in[9];
  const float* bih1 = (const float*)d_in[10];
  const float* bhh1 = (const float*)d_in[11];
  const float* fcw  = (const float*)d_in[12];
  const float* fcb  = (const float*)d_in[13];
  const float* redw = (const float*)d_in[14];
  const float* redb = (const float*)d_in[15];
  float* out = (float*)d_out;

  char* ws = (char*)d_ws;
  float*    OUTG  = (float*)(ws + 0);          // [768][1024] (read by stage-2 in k3)
  float*    OUTM  = (float*)(ws + 3145728);    // [768][256]
  float*    EXTRA = (float*)(ws + 3932160);    // [3][768]
  unsigned long long* H0P = (unsigned long long*)(ws + 3941376); // [2][512]
  unsigned long long* H1P = (unsigned long long*)(ws + 3949568); // [2][512]
  unsigned* PROG  = (unsigned*)(ws + 3957760); // producers[0..511] + S2 flags
  float*    GF    = (float*)(ws + 3960064);    // [1027][768]
  float*    MT    = (float*)(ws + 7115776);    // [256][768]
  float*    GIHS  = (float*)(ws + 7902208);    // [1024][768]
  float*    PM    = (float*)(ws + 11047936);   // [1027][768]
  float*    M2    = (float*)(ws + 14203648);   // [768][256]
  unsigned short* H1SB = (unsigned short*)(ws + 14990080); // [1024][256] bf16
  unsigned short* GF2B = (unsigned short*)(ws + 15514624); // [1024][768] bf16
  unsigned short* FB   = (unsigned short*)(ws + 17087488); // fcw bf16 [VD*256]
  float*    LOSSP = (float*)(ws + 52983808);   // [4384] own region
  const size_t NEEDED = 52983808UL + 4384UL * 4UL;
  const int s2 = (ws_size >= NEEDED) ? 1 : 0;

  // zero split-K accumulators + EXTRA + tag buffers + progress (every call)
  hipMemsetAsync(d_ws, 0, 3960064, stream);

  if (s2) {
    tobf16<<<dim3(8764), 256, 0, stream>>>(fcw, FB, 17948160L);
    // stage-1: n-blocks {0,2} + OUTM(+folded gemv), z=28 (CHK=2528), 252 blocks
    bigk_merged<<<dim3(3, 3, 28), 512, 0, stream>>>(redw, vert, fcw, tmpl, fcb, EXTRA,
                                                    OUTG, OUTM, 2528, 1);
  } else {
    bigk_merged<<<dim3(5, 3, 21), 512, 0, stream>>>(redw, vert, fcw, tmpl, fcb, EXTRA,
                                                    OUTG, OUTM, 3344, 0);
  }

  transpose_merged<<<dim3(32, 24, 2), 256, 0, stream>>>(OUTG, OUTM, EXTRA, redb, GF, MT, s2);
  gemm128x3<<<dim3(9, 6, 3), 256, 0, stream>>>(hs, wih0, GIHS, bih0, GF, PM, MT, M2, s2);

  // fused recurrence + fc GEMM + stage-2 (bigk n-blocks {1,3} -> GF2B -> PM)
  k3_fused<<<256, 512, 0, stream>>>(GIHS, PM, M2, whh0, bhh0, wih1, bih1, whh1, bhh1,
                                    tfm, H1SB, H0P, H1P, PROG,
                                    fcw, FB, s2, fcb, vert, out,
                                    s2 ? LOSSP : (float*)(ws + 0),
                                    redw, OUTG, GF2B, PM, redb, wih0 + 768);

  loss_finalize<<<1, 256, 0, stream>>>(s2 ? LOSSP : (float*)(ws + 0), 4384, out + 71792640L);
}